// Round 8
// baseline (381.720 us; speedup 1.0000x reference)
//
#include <hip/hip_runtime.h>
#include <cstdint>
#include <type_traits>
#include <utility>

// ---------------------------------------------------------------------------
// SOARALinearLayer: out = x @ (W_deq + B2@A2)^T + bias
//   A2 = lora_A @ R_v, B2 = R_u @ lora_B (butterflies folded into LoRA factors)
// => one bf16 MFMA GEMM (M=8192, N=4096, K=4096) + tiny prep.
// R7: exact R5 schedule (best: 270us, 4 waits vmcnt(8)/(6)) with MFMA shape
// switched 16x16x32 -> 32x32x16 (+15% matrix rate, half the MFMA insts,
// same LDS traffic); sched_barrier removed from VMC (asm memory clobber
// already orders memory ops; MFMA may overlap the wait).
// ---------------------------------------------------------------------------

typedef unsigned short u16;
typedef unsigned int   u32;
typedef short  s16x8 __attribute__((ext_vector_type(8)));
typedef __bf16 b16x8 __attribute__((ext_vector_type(8)));
typedef float  f32x4  __attribute__((ext_vector_type(4)));
typedef float  f32x16 __attribute__((ext_vector_type(16)));
typedef int    i32x4 __attribute__((ext_vector_type(4)));

#define SCALING 1.0f   /* ALPHA/RANK = 32/32 */

__device__ __forceinline__ u16 f2bf(float f) {
  u32 u = __builtin_bit_cast(u32, f);
  u += 0x7FFFu + ((u >> 16) & 1u);
  return (u16)(u >> 16);
}

// ---- MFMA 32x32x16 wrapper: handle i16-vector vs __bf16-vector builtin sigs
template <typename T, typename = void>
struct mfma32_takes_i16 : std::false_type {};
template <typename T>
struct mfma32_takes_i16<T, std::void_t<decltype(__builtin_amdgcn_mfma_f32_32x32x16_bf16(
    std::declval<T>(), std::declval<T>(), std::declval<f32x16>(), 0, 0, 0))>>
    : std::true_type {};

template <typename T>
__device__ __forceinline__ f32x16 mfma32(T a, T b, f32x16 c) {
  if constexpr (mfma32_takes_i16<T>::value) {
    return __builtin_amdgcn_mfma_f32_32x32x16_bf16(a, b, c, 0, 0, 0);
  } else {
    return __builtin_amdgcn_mfma_f32_32x32x16_bf16(
        __builtin_bit_cast(b16x8, a), __builtin_bit_cast(b16x8, b), c, 0, 0, 0);
  }
}

__device__ __forceinline__ void gload_lds16(const void* g, void* l) {
  __builtin_amdgcn_global_load_lds((const __attribute__((address_space(1))) u32*)g,
                                   (__attribute__((address_space(3))) u32*)l,
                                   16, 0, 0);
}

// ===========================================================================
// Kernel 1 (merged): blocks 0-31: A2 = lora_A @ R_v ; blocks 32-63: B2 = R_u@B
// ===========================================================================
__global__ __launch_bounds__(256) void k_rot(const float* __restrict__ A,
                                             const float* __restrict__ thA,
                                             const float* __restrict__ B,
                                             const float* __restrict__ thB,
                                             float* __restrict__ A2,
                                             float* __restrict__ B2) {
  __shared__ float buf[4096];
  const int t = threadIdx.x;
  if (blockIdx.x < 32) {
    const int row = blockIdx.x;
    const float* src = A + (size_t)row * 4096;
    for (int p = 0; p < 16; ++p) buf[p * 256 + t] = src[p * 256 + t];
    __syncthreads();
    for (int j = 0; j < 12; ++j) {
      const int k = 4096 >> j;
      const int half = k >> 1;
      const int lh = 11 - j;
      for (int p = 0; p < 8; ++p) {
        int tp = p * 256 + t;
        int b = tp >> lh;
        int i = tp & (half - 1);
        int pi = b * k + i;
        int qi = pi + half;
        float s, c;
        sincosf(thA[j * 2048 + tp], &s, &c);
        float xp = buf[pi], xq = buf[qi];
        buf[pi] = c * xp + s * xq;
        buf[qi] = -s * xp + c * xq;
      }
      __syncthreads();
    }
    for (int p = 0; p < 16; ++p) A2[(size_t)row * 4096 + p * 256 + t] = buf[p * 256 + t];
  } else {
    const int col = blockIdx.x - 32;
    for (int p = 0; p < 16; ++p) buf[p * 256 + t] = B[(size_t)(p * 256 + t) * 32 + col];
    __syncthreads();
    for (int j = 11; j >= 0; --j) {
      const int k = 4096 >> j;
      const int half = k >> 1;
      const int lh = 11 - j;
      for (int p = 0; p < 8; ++p) {
        int tp = p * 256 + t;
        int b = tp >> lh;
        int i = tp & (half - 1);
        int pi = b * k + i;
        int qi = pi + half;
        float s, c;
        sincosf(thB[j * 2048 + tp], &s, &c);
        float xp = buf[pi], xq = buf[qi];
        buf[pi] = c * xp - s * xq;
        buf[qi] = s * xp + c * xq;
      }
      __syncthreads();
    }
    for (int p = 0; p < 16; ++p)
      B2[(size_t)(p * 256 + t) * 32 + col] = SCALING * buf[p * 256 + t];
  }
}

// ===========================================================================
// Kernel 2: W'[n][k] = (codes-8)*scale + sum_r B2[n][r]*A2[r][k], bf16 out.
// ===========================================================================
__global__ __launch_bounds__(256) void k_wprime(const int* __restrict__ codes,
                                                const float* __restrict__ scales,
                                                const float* __restrict__ A2,
                                                const float* __restrict__ B2,
                                                u16* __restrict__ Wq) {
  __shared__ float A2s[32][128];
  __shared__ float B2t[32][128];
  const int t = threadIdx.x;
  const int n0 = (blockIdx.x >> 5) << 7;
  const int k0 = (blockIdx.x & 31) << 7;

#pragma unroll
  for (int q = 0; q < 4; ++q) {
    int f = (q * 256 + t) * 4;
    int r = f >> 7, c = f & 127;
    *(f32x4*)&A2s[r][c] = *(const f32x4*)(A2 + (size_t)r * 4096 + k0 + c);
  }
#pragma unroll
  for (int q = 0; q < 4; ++q) {
    int f = (q * 256 + t) * 4;
    int i = f >> 5, r = f & 31;
    f32x4 v = *(const f32x4*)(B2 + (size_t)(n0 + i) * 32 + r);
    B2t[r][i] = v[0]; B2t[r + 1][i] = v[1]; B2t[r + 2][i] = v[2]; B2t[r + 3][i] = v[3];
  }
  __syncthreads();

  const int tr = t >> 4, tc = t & 15;
  const int kg = k0 + tc * 8;
  float acc[8][8];
#pragma unroll
  for (int i = 0; i < 8; ++i) {
    const int n = n0 + tr * 8 + i;
    const float sc = scales[((size_t)n << 6) + (kg >> 6)];
    const i32x4 c0 = *(const i32x4*)(codes + (size_t)n * 4096 + kg);
    const i32x4 c1 = *(const i32x4*)(codes + (size_t)n * 4096 + kg + 4);
#pragma unroll
    for (int e = 0; e < 4; ++e) {
      acc[i][e]     = (float)(c0[e] - 8) * sc;
      acc[i][4 + e] = (float)(c1[e] - 8) * sc;
    }
  }
#pragma unroll
  for (int r = 0; r < 32; ++r) {
    const f32x4 a0 = *(const f32x4*)&A2s[r][tc * 8];
    const f32x4 a1 = *(const f32x4*)&A2s[r][tc * 8 + 4];
    const f32x4 b0 = *(const f32x4*)&B2t[r][tr * 8];
    const f32x4 b1 = *(const f32x4*)&B2t[r][tr * 8 + 4];
#pragma unroll
    for (int i = 0; i < 4; ++i) {
#pragma unroll
      for (int e = 0; e < 4; ++e) {
        acc[i][e]         += b0[i] * a0[e];
        acc[i][4 + e]     += b0[i] * a1[e];
        acc[4 + i][e]     += b1[i] * a0[e];
        acc[4 + i][4 + e] += b1[i] * a1[e];
      }
    }
  }
#pragma unroll
  for (int i = 0; i < 8; ++i) {
    const int n = n0 + tr * 8 + i;
    s16x8 o;
#pragma unroll
    for (int e = 0; e < 8; ++e) o[e] = (short)f2bf(acc[i][e]);
    *(s16x8*)(Wq + (size_t)n * 4096 + kg) = o;
  }
}

// ===========================================================================
// Kernel 3: x (f32) -> bf16
// ===========================================================================
__global__ __launch_bounds__(256) void k_xbf16(const float* __restrict__ x,
                                               u16* __restrict__ xb) {
  const size_t i = ((size_t)blockIdx.x * 256 + threadIdx.x) * 8;
  f32x4 a = *(const f32x4*)(x + i);
  f32x4 b = *(const f32x4*)(x + i + 4);
  s16x8 o;
  o[0] = (short)f2bf(a[0]); o[1] = (short)f2bf(a[1]);
  o[2] = (short)f2bf(a[2]); o[3] = (short)f2bf(a[3]);
  o[4] = (short)f2bf(b[0]); o[5] = (short)f2bf(b[1]);
  o[6] = (short)f2bf(b[2]); o[7] = (short)f2bf(b[3]);
  *(s16x8*)(xb + i) = o;
}

// ===========================================================================
// Main GEMM, 256x256 tile, BK=64, 8-phase, R5 stage/wait schedule, 32x32x16.
// Per wave (2Mx4N grid, out 128x64): per phase (QM,QN): 2 rowblocks(32) x
// 1 colblock(32) x 4 ksteps(16) = 8 MFMA. Reads: 8 a-frags + 4 b-frags (b
// kept in regs QN0: p1->p4, p5->p8).
// A-frag: lane=row l&31, k=(l>>5)*8+e; B-frag: col l&31, same k.
// C/D: col=l&31, row=(v&3)+8*(v>>2)+4*(l>>5), v in [0,16).
// Stage order + waits: identical to R5 (queue-simulated safe):
//   S1@p1 buf1.B0(k+1)  S2@p2 buf1.A1(k+1) VMC(8)
//   S3@p3 buf0.A0(k+2)  S4@p4 buf0.B1(k+2) VMC(6)
//   S5@p5 buf0.B0(k+2)  S6@p6 buf0.A1(k+2) VMC(8)
//   S7@p7 buf1.A0(k+3)  S8@p8 buf1.B1(k+3) VMC(6)
// ===========================================================================
#define BAR()    __builtin_amdgcn_s_barrier()
#define VMC(n)   asm volatile("s_waitcnt vmcnt(" #n ")" ::: "memory")

template <int QM>
__device__ __forceinline__ void load_a32(s16x8 a[2][4], const u16* as, int wm, int lane) {
  const int rl = lane & 31, g = lane >> 5;
#pragma unroll
  for (int rb = 0; rb < 2; ++rb) {
    const int row = QM * 128 + wm + rb * 32 + rl;
#pragma unroll
    for (int ks = 0; ks < 4; ++ks) {
      const int slot = ks * 2 + g;
      a[rb][ks] = *(const s16x8*)(as + row * 64 + ((slot ^ (row & 7)) << 3));
    }
  }
}

template <int QN>
__device__ __forceinline__ void load_b32(s16x8 b[4], const u16* bs, int wn, int lane) {
  const int rl = lane & 31, g = lane >> 5;
  const int row = QN * 128 + wn + rl;
#pragma unroll
  for (int ks = 0; ks < 4; ++ks) {
    const int slot = ks * 2 + g;
    b[ks] = *(const s16x8*)(bs + row * 64 + ((slot ^ (row & 7)) << 3));
  }
}

template <int QM, int QN>
__device__ __forceinline__ void mma8(f32x16 acc[4][2], s16x8 a[2][4], s16x8 b[4]) {
  __builtin_amdgcn_s_setprio(1);
#pragma unroll
  for (int ks = 0; ks < 4; ++ks)
#pragma unroll
    for (int rb = 0; rb < 2; ++rb)
      acc[QM * 2 + rb][QN] = mfma32(a[rb][ks], b[ks], acc[QM * 2 + rb][QN]);
  __builtin_amdgcn_s_setprio(0);
}

__global__ __launch_bounds__(512, 2) void k_gemm8(const u16* __restrict__ Abf,
                                                  const u16* __restrict__ Bbf,
                                                  const float* __restrict__ bias,
                                                  float* __restrict__ out) {
  __shared__ __align__(16) u16 As[2][256 * 64];
  __shared__ __align__(16) u16 Bs[2][256 * 64];

  const int bid = blockIdx.x;
  const int wg = (bid & 7) * 64 + (bid >> 3);   // 512 % 8 == 0: bijective XCD swizzle
  const int mt = wg >> 4, nt = wg & 15;
  const int m0 = mt << 8, n0 = nt << 8;
  const int tid = threadIdx.x;
  const int lane = tid & 63;
  const int wid = tid >> 6;
  const int wm = (wid >> 2) * 64;   // row sub-offset within each 128-row half
  const int wn = (wid & 3) * 32;    // col sub-offset within each 128-col half

  int rowc[2], swzc[2];
#pragma unroll
  for (int c = 0; c < 2; ++c) {
    const int flat = (c * 512 + tid) * 8;
    rowc[c] = flat >> 6;
    const int slot = (flat >> 3) & 7;
    swzc[c] = (slot ^ (rowc[c] & 7)) << 3;   // inverse-swizzled global source
  }
  const u16* Ap0 = Abf + ((size_t)m0) * 4096;
  const u16* Ap1 = Abf + ((size_t)(m0 + 128)) * 4096;
  const u16* Bp0 = Bbf + ((size_t)n0) * 4096;
  const u16* Bp1 = Bbf + ((size_t)(n0 + 128)) * 4096;

#define STAGE(gpan, kt, ldsbase)                                              \
  do {                                                                        \
    _Pragma("unroll")                                                         \
    for (int c = 0; c < 2; ++c)                                               \
      gload_lds16((gpan) + (size_t)rowc[c] * 4096 + (kt) * 64 + swzc[c],      \
                  (ldsbase) + (c * 512 + tid) * 8);                           \
  } while (0)

  f32x16 acc[4][2] = {};   // [QM*2+rb][QN]
  s16x8 a[2][4], b0[4], b1[4];

  // ---- prologue: K0 full -> buf0; K1.A0 -> buf1.A0; K1.B1 -> buf1.B1 ----
  STAGE(Ap0, 0, As[0]);
  STAGE(Ap1, 0, As[0] + 8192);
  STAGE(Bp0, 0, Bs[0]);
  STAGE(Bp1, 0, Bs[0] + 8192);
  STAGE(Ap0, 1, As[1]);
  STAGE(Bp1, 1, Bs[1] + 8192);
  VMC(4);          // buf0 (8 ops) landed; buf1.A0/B1 may remain in flight
  BAR();

#pragma unroll 1
  for (int it = 0; it < 32; ++it) {
    const int kn1 = 2 * it + 1;
    const int ktA = (2 * it + 2 < 64) ? 2 * it + 2 : 63;  // clamped tail (dead stages)
    const int ktB = (2 * it + 3 < 64) ? 2 * it + 3 : 63;

    // ---- p1: (0,0) a,b0 from buf0; S1: buf1.B0 <- K(2it+1) ----
    load_a32<0>(a, As[0], wm, lane);
    load_b32<0>(b0, Bs[0], wn, lane);
    STAGE(Bp0, kn1, Bs[1]);
    BAR();
    mma8<0, 0>(acc, a, b0);
    BAR();
    // ---- p2: (0,1) b1 from buf0; S2: buf1.A1 <- K(2it+1); vmcnt(8) ----
    load_b32<1>(b1, Bs[0], wn, lane);
    STAGE(Ap1, kn1, As[1] + 8192);
    BAR();
    mma8<0, 1>(acc, a, b1);
    VMC(8);
    BAR();
    // ---- p3: (1,1) a from buf0.A1; S3: buf0.A0 <- K(2it+2) ----
    load_a32<1>(a, As[0], wm, lane);
    STAGE(Ap0, ktA, As[0]);
    BAR();
    mma8<1, 1>(acc, a, b1);
    BAR();
    // ---- p4: (1,0) kept b0 (no ds_reads); S4: buf0.B1; vmcnt(6) ----
    STAGE(Bp1, ktA, Bs[0] + 8192);
    BAR();
    mma8<1, 0>(acc, a, b0);
    VMC(6);
    BAR();
    // ---- p5: (0,0) from buf1; S5: buf0.B0 <- K(2it+2) ----
    load_a32<0>(a, As[1], wm, lane);
    load_b32<0>(b0, Bs[1], wn, lane);
    STAGE(Bp0, ktA, Bs[0]);
    BAR();
    mma8<0, 0>(acc, a, b0);
    BAR();
    // ---- p6: (0,1) from buf1; S6: buf0.A1 <- K(2it+2); vmcnt(8) ----
    load_b32<1>(b1, Bs[1], wn, lane);
    STAGE(Ap1, ktA, As[0] + 8192);
    BAR();
    mma8<0, 1>(acc, a, b1);
    VMC(8);
    BAR();
    // ---- p7: (1,1) from buf1; S7: buf1.A0 <- K(2it+3) ----
    load_a32<1>(a, As[1], wm, lane);
    STAGE(Ap0, ktB, As[1]);
    BAR();
    mma8<1, 1>(acc, a, b1);
    BAR();
    // ---- p8: (1,0) kept b0 (no ds_reads); S8: buf1.B1; vmcnt(6) ----
    STAGE(Bp1, ktB, Bs[1] + 8192);
    BAR();
    mma8<1, 0>(acc, a, b0);
    VMC(6);
    BAR();
  }
  VMC(0);  // drain tail dead stages before epilogue

  // ---- epilogue: C/D col = lane&31, row = (v&3)+8*(v>>2)+4*(lane>>5) ----
  const int rl = lane & 31, g = lane >> 5;
  float bv[2];
#pragma unroll
  for (int qn = 0; qn < 2; ++qn)
    bv[qn] = bias[n0 + qn * 128 + wn + rl];
#pragma unroll
  for (int i = 0; i < 4; ++i) {   // i = QM*2 + rb
    const int rbase = m0 + (i >> 1) * 128 + wm + (i & 1) * 32 + g * 4;
#pragma unroll
    for (int qn = 0; qn < 2; ++qn) {
      const int col = n0 + qn * 128 + wn + rl;
#pragma unroll
      for (int v = 0; v < 16; ++v) {
        const int row = rbase + (v & 3) + 8 * (v >> 2);
        out[(size_t)row * 4096 + col] = acc[i][qn][v] + bv[qn];
      }
    }
  }
#undef STAGE
}

// ===========================================================================
extern "C" void kernel_launch(void* const* d_in, const int* in_sizes, int n_in,
                              void* d_out, int out_size, void* d_ws, size_t ws_size,
                              hipStream_t stream) {
  const float* x      = (const float*)d_in[0];
  const int*   codes  = (const int*)d_in[1];
  const float* scales = (const float*)d_in[2];
  const float* th_v   = (const float*)d_in[3];
  const float* th_u   = (const float*)d_in[4];
  const float* lA     = (const float*)d_in[5];
  const float* lB     = (const float*)d_in[6];
  const float* bias   = (const float*)d_in[7];
  float* out = (float*)d_out;

  char* ws = (char*)d_ws;
  float* A2 = (float*)ws;                              // 512 KB
  float* B2 = (float*)(ws + (512u << 10));             // 512 KB
  u16*   Wq = (u16*)(ws + (1u << 20));                 // 32 MB
  u16*   xb = (u16*)(ws + (1u << 20) + (32u << 20));   // 64 MB

  k_rot<<<64, 256, 0, stream>>>(lA, th_v, lB, th_u, A2, B2);
  k_wprime<<<1024, 256, 0, stream>>>(codes, scales, A2, B2, Wq);
  k_xbf16<<<16384, 256, 0, stream>>>(x, xb);
  k_gemm8<<<512, 512, 0, stream>>>(xb, Wq, bias, out);
}

// Round 9
// 347.703 us; speedup vs baseline: 1.0978x; 1.0978x over previous
//
#include <hip/hip_runtime.h>
#include <cstdint>
#include <type_traits>
#include <utility>

// ---------------------------------------------------------------------------
// SOARALinearLayer: out = x @ (W_deq + B2@A2)^T + bias
//   A2 = lora_A @ R_v, B2 = R_u @ lora_B (butterflies folded into LoRA factors)
// => one bf16 MFMA GEMM (M=8192, N=4096, K=4096) + tiny prep.
// R9: GEMM reverted to exact R5 champion (270us, 16x16x32, 4-wait schedule,
// 0 bank conflicts; R8's 32x32 shape hit 2.5e7 conflicts and regressed).
// Prep: k_rot fused into k_xbf16's launch (independent writes, no cross-block
// reads -> race-free); rot latency hides under the BW-bound conversion.
// ---------------------------------------------------------------------------

typedef unsigned short u16;
typedef unsigned int   u32;
typedef short  s16x8 __attribute__((ext_vector_type(8)));
typedef __bf16 b16x8 __attribute__((ext_vector_type(8)));
typedef float  f32x4 __attribute__((ext_vector_type(4)));
typedef int    i32x4 __attribute__((ext_vector_type(4)));

#define SCALING 1.0f   /* ALPHA/RANK = 32/32 */

__device__ __forceinline__ u16 f2bf(float f) {
  u32 u = __builtin_bit_cast(u32, f);
  u += 0x7FFFu + ((u >> 16) & 1u);
  return (u16)(u >> 16);
}

template <typename T, typename = void>
struct mfma_takes_i16 : std::false_type {};
template <typename T>
struct mfma_takes_i16<T, std::void_t<decltype(__builtin_amdgcn_mfma_f32_16x16x32_bf16(
    std::declval<T>(), std::declval<T>(), std::declval<f32x4>(), 0, 0, 0))>>
    : std::true_type {};

template <typename T>
__device__ __forceinline__ f32x4 mfma_bf16(T a, T b, f32x4 c) {
  if constexpr (mfma_takes_i16<T>::value) {
    return __builtin_amdgcn_mfma_f32_16x16x32_bf16(a, b, c, 0, 0, 0);
  } else {
    return __builtin_amdgcn_mfma_f32_16x16x32_bf16(
        __builtin_bit_cast(b16x8, a), __builtin_bit_cast(b16x8, b), c, 0, 0, 0);
  }
}

__device__ __forceinline__ void gload_lds16(const void* g, void* l) {
  __builtin_amdgcn_global_load_lds((const __attribute__((address_space(1))) u32*)g,
                                   (__attribute__((address_space(3))) u32*)l,
                                   16, 0, 0);
}

// ===========================================================================
// Kernel 1 (merged prep): blocks 0-31: A2 = lora_A @ R_v (row rotations);
// blocks 32-63: B2 = R_u @ lora_B (col rotations); blocks 64..2111: x->bf16.
// All outputs disjoint; no cross-block reads -> race-free in one launch.
// ===========================================================================
__global__ __launch_bounds__(256) void k_prep(const float* __restrict__ A,
                                              const float* __restrict__ thA,
                                              const float* __restrict__ B,
                                              const float* __restrict__ thB,
                                              const float* __restrict__ x,
                                              float* __restrict__ A2,
                                              float* __restrict__ B2,
                                              u16* __restrict__ xb) {
  const int t = threadIdx.x;
  if (blockIdx.x >= 64) {
    // ---- x (f32) -> bf16, grid-stride: 2048 blocks x 8 iters x 8 elem ----
    const size_t stride = (size_t)2048 * 256 * 8;
    size_t i = ((size_t)(blockIdx.x - 64) * 256 + t) * 8;
#pragma unroll
    for (int it = 0; it < 8; ++it, i += stride) {
      f32x4 a = *(const f32x4*)(x + i);
      f32x4 b = *(const f32x4*)(x + i + 4);
      s16x8 o;
      o[0] = (short)f2bf(a[0]); o[1] = (short)f2bf(a[1]);
      o[2] = (short)f2bf(a[2]); o[3] = (short)f2bf(a[3]);
      o[4] = (short)f2bf(b[0]); o[5] = (short)f2bf(b[1]);
      o[6] = (short)f2bf(b[2]); o[7] = (short)f2bf(b[3]);
      *(s16x8*)(xb + i) = o;
    }
    return;
  }
  __shared__ float buf[4096];
  if (blockIdx.x < 32) {
    const int row = blockIdx.x;
    const float* src = A + (size_t)row * 4096;
    for (int p = 0; p < 16; ++p) buf[p * 256 + t] = src[p * 256 + t];
    __syncthreads();
    for (int j = 0; j < 12; ++j) {
      const int k = 4096 >> j;
      const int half = k >> 1;
      const int lh = 11 - j;
      for (int p = 0; p < 8; ++p) {
        int tp = p * 256 + t;
        int b = tp >> lh;
        int i = tp & (half - 1);
        int pi = b * k + i;
        int qi = pi + half;
        float s, c;
        sincosf(thA[j * 2048 + tp], &s, &c);
        float xp = buf[pi], xq = buf[qi];
        buf[pi] = c * xp + s * xq;
        buf[qi] = -s * xp + c * xq;
      }
      __syncthreads();
    }
    for (int p = 0; p < 16; ++p) A2[(size_t)row * 4096 + p * 256 + t] = buf[p * 256 + t];
  } else {
    const int col = blockIdx.x - 32;
    for (int p = 0; p < 16; ++p) buf[p * 256 + t] = B[(size_t)(p * 256 + t) * 32 + col];
    __syncthreads();
    for (int j = 11; j >= 0; --j) {
      const int k = 4096 >> j;
      const int half = k >> 1;
      const int lh = 11 - j;
      for (int p = 0; p < 8; ++p) {
        int tp = p * 256 + t;
        int b = tp >> lh;
        int i = tp & (half - 1);
        int pi = b * k + i;
        int qi = pi + half;
        float s, c;
        sincosf(thB[j * 2048 + tp], &s, &c);
        float xp = buf[pi], xq = buf[qi];
        buf[pi] = c * xp - s * xq;
        buf[qi] = s * xp + c * xq;
      }
      __syncthreads();
    }
    for (int p = 0; p < 16; ++p)
      B2[(size_t)(p * 256 + t) * 32 + col] = SCALING * buf[p * 256 + t];
  }
}

// ===========================================================================
// Kernel 2: W'[n][k] = (codes-8)*scale + sum_r B2[n][r]*A2[r][k], bf16 out.
// ===========================================================================
__global__ __launch_bounds__(256) void k_wprime(const int* __restrict__ codes,
                                                const float* __restrict__ scales,
                                                const float* __restrict__ A2,
                                                const float* __restrict__ B2,
                                                u16* __restrict__ Wq) {
  __shared__ float A2s[32][128];
  __shared__ float B2t[32][128];
  const int t = threadIdx.x;
  const int n0 = (blockIdx.x >> 5) << 7;
  const int k0 = (blockIdx.x & 31) << 7;

#pragma unroll
  for (int q = 0; q < 4; ++q) {
    int f = (q * 256 + t) * 4;
    int r = f >> 7, c = f & 127;
    *(f32x4*)&A2s[r][c] = *(const f32x4*)(A2 + (size_t)r * 4096 + k0 + c);
  }
#pragma unroll
  for (int q = 0; q < 4; ++q) {
    int f = (q * 256 + t) * 4;
    int i = f >> 5, r = f & 31;
    f32x4 v = *(const f32x4*)(B2 + (size_t)(n0 + i) * 32 + r);
    B2t[r][i] = v[0]; B2t[r + 1][i] = v[1]; B2t[r + 2][i] = v[2]; B2t[r + 3][i] = v[3];
  }
  __syncthreads();

  const int tr = t >> 4, tc = t & 15;
  const int kg = k0 + tc * 8;
  float acc[8][8];
#pragma unroll
  for (int i = 0; i < 8; ++i) {
    const int n = n0 + tr * 8 + i;
    const float sc = scales[((size_t)n << 6) + (kg >> 6)];
    const i32x4 c0 = *(const i32x4*)(codes + (size_t)n * 4096 + kg);
    const i32x4 c1 = *(const i32x4*)(codes + (size_t)n * 4096 + kg + 4);
#pragma unroll
    for (int e = 0; e < 4; ++e) {
      acc[i][e]     = (float)(c0[e] - 8) * sc;
      acc[i][4 + e] = (float)(c1[e] - 8) * sc;
    }
  }
#pragma unroll
  for (int r = 0; r < 32; ++r) {
    const f32x4 a0 = *(const f32x4*)&A2s[r][tc * 8];
    const f32x4 a1 = *(const f32x4*)&A2s[r][tc * 8 + 4];
    const f32x4 b0 = *(const f32x4*)&B2t[r][tr * 8];
    const f32x4 b1 = *(const f32x4*)&B2t[r][tr * 8 + 4];
#pragma unroll
    for (int i = 0; i < 4; ++i) {
#pragma unroll
      for (int e = 0; e < 4; ++e) {
        acc[i][e]         += b0[i] * a0[e];
        acc[i][4 + e]     += b0[i] * a1[e];
        acc[4 + i][e]     += b1[i] * a0[e];
        acc[4 + i][4 + e] += b1[i] * a1[e];
      }
    }
  }
#pragma unroll
  for (int i = 0; i < 8; ++i) {
    const int n = n0 + tr * 8 + i;
    s16x8 o;
#pragma unroll
    for (int e = 0; e < 8; ++e) o[e] = (short)f2bf(acc[i][e]);
    *(s16x8*)(Wq + (size_t)n * 4096 + kg) = o;
  }
}

// ===========================================================================
// Main GEMM, 256x256 tile, BK=64, 8-phase — EXACT R5 champion (270us).
// Stage order (iter it: buf0=K(2it) phases 1-4, buf1=K(2it+1) phases 5-8):
//   S1@p1 -> buf1.B0(2it+1)   S2@p2 -> buf1.A1(2it+1)
//   S3@p3 -> buf0.A0(2it+2)   S4@p4 -> buf0.B1(2it+2)
//   S5@p5 -> buf0.B0(2it+2)   S6@p6 -> buf0.A1(2it+2)
//   S7@p7 -> buf1.A0(2it+3)   S8@p8 -> buf1.B1(2it+3)
// Waits: vmcnt(8)@p2, vmcnt(6)@p4, vmcnt(8)@p6, vmcnt(6)@p8.
// B0 fragments held in regs p1->p4 / p5->p8 (p4/p8 have zero ds_reads).
// ===========================================================================
#define BAR()    __builtin_amdgcn_s_barrier()
#define VMC(n)   do { asm volatile("s_waitcnt vmcnt(" #n ")" ::: "memory"); \
                      __builtin_amdgcn_sched_barrier(0); } while (0)

template <int QM>
__device__ __forceinline__ void load_a(s16x8 a[4][2], const u16* as, int wm, int lane) {
  const int rl = lane & 15, sl = lane >> 4;
#pragma unroll
  for (int i = 0; i < 4; ++i) {
    const int row = QM * 128 + wm + i * 16 + rl;
#pragma unroll
    for (int kk = 0; kk < 2; ++kk) {
      const int slot = kk * 4 + sl;
      a[i][kk] = *(const s16x8*)(as + row * 64 + ((slot ^ (row & 7)) << 3));
    }
  }
}

template <int QN>
__device__ __forceinline__ void load_b(s16x8 b[2][2], const u16* bs, int wn, int lane) {
  const int rl = lane & 15, sl = lane >> 4;
#pragma unroll
  for (int j = 0; j < 2; ++j) {
    const int row = QN * 128 + wn + j * 16 + rl;
#pragma unroll
    for (int kk = 0; kk < 2; ++kk) {
      const int slot = kk * 4 + sl;
      b[j][kk] = *(const s16x8*)(bs + row * 64 + ((slot ^ (row & 7)) << 3));
    }
  }
}

template <int QM, int QN>
__device__ __forceinline__ void mma16(f32x4 acc[8][4], s16x8 a[4][2], s16x8 b[2][2]) {
  __builtin_amdgcn_s_setprio(1);
#pragma unroll
  for (int kk = 0; kk < 2; ++kk)
#pragma unroll
    for (int i = 0; i < 4; ++i)
#pragma unroll
      for (int j = 0; j < 2; ++j)
        acc[QM * 4 + i][QN * 2 + j] = mfma_bf16(a[i][kk], b[j][kk], acc[QM * 4 + i][QN * 2 + j]);
  __builtin_amdgcn_s_setprio(0);
}

__global__ __launch_bounds__(512, 2) void k_gemm8(const u16* __restrict__ Abf,
                                                  const u16* __restrict__ Bbf,
                                                  const float* __restrict__ bias,
                                                  float* __restrict__ out) {
  __shared__ __align__(16) u16 As[2][256 * 64];
  __shared__ __align__(16) u16 Bs[2][256 * 64];

  const int bid = blockIdx.x;
  const int wg = (bid & 7) * 64 + (bid >> 3);   // 512 % 8 == 0: bijective XCD swizzle
  const int mt = wg >> 4, nt = wg & 15;
  const int m0 = mt << 8, n0 = nt << 8;
  const int tid = threadIdx.x;
  const int lane = tid & 63;
  const int wid = tid >> 6;
  const int wm = (wid >> 2) * 64;   // row sub-offset within each 128-row half
  const int wn = (wid & 3) * 32;    // col sub-offset within each 128-col half

  int rowc[2], swzc[2];
#pragma unroll
  for (int c = 0; c < 2; ++c) {
    const int flat = (c * 512 + tid) * 8;
    rowc[c] = flat >> 6;
    const int slot = (flat >> 3) & 7;
    swzc[c] = (slot ^ (rowc[c] & 7)) << 3;   // inverse-swizzled global source
  }
  const u16* Ap0 = Abf + ((size_t)m0) * 4096;
  const u16* Ap1 = Abf + ((size_t)(m0 + 128)) * 4096;
  const u16* Bp0 = Bbf + ((size_t)n0) * 4096;
  const u16* Bp1 = Bbf + ((size_t)(n0 + 128)) * 4096;

#define STAGE(gpan, kt, ldsbase)                                              \
  do {                                                                        \
    _Pragma("unroll")                                                         \
    for (int c = 0; c < 2; ++c)                                               \
      gload_lds16((gpan) + (size_t)rowc[c] * 4096 + (kt) * 64 + swzc[c],      \
                  (ldsbase) + (c * 512 + tid) * 8);                           \
  } while (0)

  f32x4 acc[8][4] = {};
  s16x8 a[4][2], b0[2][2], b1[2][2];

  // ---- prologue: K0 full -> buf0; K1.A0 -> buf1.A0; K1.B1 -> buf1.B1 ----
  STAGE(Ap0, 0, As[0]);
  STAGE(Ap1, 0, As[0] + 8192);
  STAGE(Bp0, 0, Bs[0]);
  STAGE(Bp1, 0, Bs[0] + 8192);
  STAGE(Ap0, 1, As[1]);
  STAGE(Bp1, 1, Bs[1] + 8192);
  VMC(4);          // buf0 (8 ops) landed; buf1.A0/B1 may remain in flight
  BAR();

#pragma unroll 1
  for (int it = 0; it < 32; ++it) {
    const int kn1 = 2 * it + 1;
    const int ktA = (2 * it + 2 < 64) ? 2 * it + 2 : 63;  // clamped tail (dead stages)
    const int ktB = (2 * it + 3 < 64) ? 2 * it + 3 : 63;

    // ---- p1: (0,0) a,b0 from buf0; S1: buf1.B0 <- K(2it+1) ----
    load_a<0>(a, As[0], wm, lane);
    load_b<0>(b0, Bs[0], wn, lane);
    STAGE(Bp0, kn1, Bs[1]);
    BAR();
    mma16<0, 0>(acc, a, b0);
    BAR();
    // ---- p2: (0,1) b1 from buf0; S2: buf1.A1 <- K(2it+1); vmcnt(8) ----
    load_b<1>(b1, Bs[0], wn, lane);
    STAGE(Ap1, kn1, As[1] + 8192);
    BAR();
    mma16<0, 1>(acc, a, b1);
    VMC(8);
    BAR();
    // ---- p3: (1,1) a from buf0.A1; S3: buf0.A0 <- K(2it+2) ----
    load_a<1>(a, As[0], wm, lane);
    STAGE(Ap0, ktA, As[0]);
    BAR();
    mma16<1, 1>(acc, a, b1);
    BAR();
    // ---- p4: (1,0) kept b0 (no ds_reads); S4: buf0.B1; vmcnt(6) ----
    STAGE(Bp1, ktA, Bs[0] + 8192);
    BAR();
    mma16<1, 0>(acc, a, b0);
    VMC(6);
    BAR();
    // ---- p5: (0,0) from buf1; S5: buf0.B0 <- K(2it+2) ----
    load_a<0>(a, As[1], wm, lane);
    load_b<0>(b0, Bs[1], wn, lane);
    STAGE(Bp0, ktA, Bs[0]);
    BAR();
    mma16<0, 0>(acc, a, b0);
    BAR();
    // ---- p6: (0,1) from buf1; S6: buf0.A1 <- K(2it+2); vmcnt(8) ----
    load_b<1>(b1, Bs[1], wn, lane);
    STAGE(Ap1, ktA, As[0] + 8192);
    BAR();
    mma16<0, 1>(acc, a, b1);
    VMC(8);
    BAR();
    // ---- p7: (1,1) from buf1; S7: buf1.A0 <- K(2it+3) ----
    load_a<1>(a, As[1], wm, lane);
    STAGE(Ap0, ktB, As[1]);
    BAR();
    mma16<1, 1>(acc, a, b1);
    BAR();
    // ---- p8: (1,0) kept b0 (no ds_reads); S8: buf1.B1; vmcnt(6) ----
    STAGE(Bp1, ktB, Bs[1] + 8192);
    BAR();
    mma16<1, 0>(acc, a, b0);
    VMC(6);
    BAR();
  }

  // ---- epilogue: C/D layout col = lane&15, row = (lane>>4)*4 + v ----
  const int rl = lane & 15, rg = lane >> 4;
  float bv[4];
#pragma unroll
  for (int j = 0; j < 4; ++j)
    bv[j] = bias[n0 + (j >> 1) * 128 + wn + (j & 1) * 16 + rl];
#pragma unroll
  for (int i = 0; i < 8; ++i) {
    const int row0 = m0 + (i >> 2) * 128 + wm + (i & 3) * 16 + rg * 4;
#pragma unroll
    for (int j = 0; j < 4; ++j) {
      const int col = n0 + (j >> 1) * 128 + wn + (j & 1) * 16 + rl;
#pragma unroll
      for (int v = 0; v < 4; ++v)
        out[(size_t)(row0 + v) * 4096 + col] = acc[i][j][v] + bv[j];
    }
  }
#undef STAGE
}

// ===========================================================================
extern "C" void kernel_launch(void* const* d_in, const int* in_sizes, int n_in,
                              void* d_out, int out_size, void* d_ws, size_t ws_size,
                              hipStream_t stream) {
  const float* x      = (const float*)d_in[0];
  const int*   codes  = (const int*)d_in[1];
  const float* scales = (const float*)d_in[2];
  const float* th_v   = (const float*)d_in[3];
  const float* th_u   = (const float*)d_in[4];
  const float* lA     = (const float*)d_in[5];
  const float* lB     = (const float*)d_in[6];
  const float* bias   = (const float*)d_in[7];
  float* out = (float*)d_out;

  char* ws = (char*)d_ws;
  float* A2 = (float*)ws;                              // 512 KB
  float* B2 = (float*)(ws + (512u << 10));             // 512 KB
  u16*   Wq = (u16*)(ws + (1u << 20));                 // 32 MB
  u16*   xb = (u16*)(ws + (1u << 20) + (32u << 20));   // 64 MB

  k_prep<<<2112, 256, 0, stream>>>(lA, th_v, lB, th_u, x, A2, B2, xb);
  k_wprime<<<1024, 256, 0, stream>>>(codes, scales, A2, B2, Wq);
  k_gemm8<<<512, 512, 0, stream>>>(xb, Wq, bias, out);
}

// Round 11
// 337.953 us; speedup vs baseline: 1.1295x; 1.0289x over previous
//
#include <hip/hip_runtime.h>
#include <cstdint>
#include <type_traits>
#include <utility>

// ---------------------------------------------------------------------------
// SOARALinearLayer: out = x @ (W_deq + B2@A2)^T + bias
//   A2 = lora_A @ R_v, B2 = R_u @ lora_B (butterflies folded into LoRA factors)
// => one bf16 MFMA GEMM (M=8192, N=4096, K=4096) + tiny prep.
// R10: merge the 8 phases into 4 segments (p1+p2, p3+p4, p5+p6, p7+p8).
// Identical instruction order and vmcnt wait positions as the R5 champion
// (queue-sim verified), but 4 barriers/K-tile instead of 16 — each segment
// holds 32 MFMA + its ds_reads so read latency drains under MFMA.
// ---------------------------------------------------------------------------

typedef unsigned short u16;
typedef unsigned int   u32;
typedef short  s16x8 __attribute__((ext_vector_type(8)));
typedef __bf16 b16x8 __attribute__((ext_vector_type(8)));
typedef float  f32x4 __attribute__((ext_vector_type(4)));
typedef int    i32x4 __attribute__((ext_vector_type(4)));

#define SCALING 1.0f   /* ALPHA/RANK = 32/32 */

__device__ __forceinline__ u16 f2bf(float f) {
  u32 u = __builtin_bit_cast(u32, f);
  u += 0x7FFFu + ((u >> 16) & 1u);
  return (u16)(u >> 16);
}

template <typename T, typename = void>
struct mfma_takes_i16 : std::false_type {};
template <typename T>
struct mfma_takes_i16<T, std::void_t<decltype(__builtin_amdgcn_mfma_f32_16x16x32_bf16(
    std::declval<T>(), std::declval<T>(), std::declval<f32x4>(), 0, 0, 0))>>
    : std::true_type {};

template <typename T>
__device__ __forceinline__ f32x4 mfma_bf16(T a, T b, f32x4 c) {
  if constexpr (mfma_takes_i16<T>::value) {
    return __builtin_amdgcn_mfma_f32_16x16x32_bf16(a, b, c, 0, 0, 0);
  } else {
    return __builtin_amdgcn_mfma_f32_16x16x32_bf16(
        __builtin_bit_cast(b16x8, a), __builtin_bit_cast(b16x8, b), c, 0, 0, 0);
  }
}

__device__ __forceinline__ void gload_lds16(const void* g, void* l) {
  __builtin_amdgcn_global_load_lds((const __attribute__((address_space(1))) u32*)g,
                                   (__attribute__((address_space(3))) u32*)l,
                                   16, 0, 0);
}

// ===========================================================================
// Kernel 1 (merged prep): blocks 0-31: A2 = lora_A @ R_v (row rotations);
// blocks 32-63: B2 = R_u @ lora_B (col rotations); blocks 64..2111: x->bf16.
// All outputs disjoint; no cross-block reads -> race-free in one launch.
// ===========================================================================
__global__ __launch_bounds__(256) void k_prep(const float* __restrict__ A,
                                              const float* __restrict__ thA,
                                              const float* __restrict__ B,
                                              const float* __restrict__ thB,
                                              const float* __restrict__ x,
                                              float* __restrict__ A2,
                                              float* __restrict__ B2,
                                              u16* __restrict__ xb) {
  const int t = threadIdx.x;
  if (blockIdx.x >= 64) {
    const size_t stride = (size_t)2048 * 256 * 8;
    size_t i = ((size_t)(blockIdx.x - 64) * 256 + t) * 8;
#pragma unroll
    for (int it = 0; it < 8; ++it, i += stride) {
      f32x4 a = *(const f32x4*)(x + i);
      f32x4 b = *(const f32x4*)(x + i + 4);
      s16x8 o;
      o[0] = (short)f2bf(a[0]); o[1] = (short)f2bf(a[1]);
      o[2] = (short)f2bf(a[2]); o[3] = (short)f2bf(a[3]);
      o[4] = (short)f2bf(b[0]); o[5] = (short)f2bf(b[1]);
      o[6] = (short)f2bf(b[2]); o[7] = (short)f2bf(b[3]);
      *(s16x8*)(xb + i) = o;
    }
    return;
  }
  __shared__ float buf[4096];
  if (blockIdx.x < 32) {
    const int row = blockIdx.x;
    const float* src = A + (size_t)row * 4096;
    for (int p = 0; p < 16; ++p) buf[p * 256 + t] = src[p * 256 + t];
    __syncthreads();
    for (int j = 0; j < 12; ++j) {
      const int k = 4096 >> j;
      const int half = k >> 1;
      const int lh = 11 - j;
      for (int p = 0; p < 8; ++p) {
        int tp = p * 256 + t;
        int b = tp >> lh;
        int i = tp & (half - 1);
        int pi = b * k + i;
        int qi = pi + half;
        float s, c;
        sincosf(thA[j * 2048 + tp], &s, &c);
        float xp = buf[pi], xq = buf[qi];
        buf[pi] = c * xp + s * xq;
        buf[qi] = -s * xp + c * xq;
      }
      __syncthreads();
    }
    for (int p = 0; p < 16; ++p) A2[(size_t)row * 4096 + p * 256 + t] = buf[p * 256 + t];
  } else {
    const int col = blockIdx.x - 32;
    for (int p = 0; p < 16; ++p) buf[p * 256 + t] = B[(size_t)(p * 256 + t) * 32 + col];
    __syncthreads();
    for (int j = 11; j >= 0; --j) {
      const int k = 4096 >> j;
      const int half = k >> 1;
      const int lh = 11 - j;
      for (int p = 0; p < 8; ++p) {
        int tp = p * 256 + t;
        int b = tp >> lh;
        int i = tp & (half - 1);
        int pi = b * k + i;
        int qi = pi + half;
        float s, c;
        sincosf(thB[j * 2048 + tp], &s, &c);
        float xp = buf[pi], xq = buf[qi];
        buf[pi] = c * xp - s * xq;
        buf[qi] = s * xp + c * xq;
      }
      __syncthreads();
    }
    for (int p = 0; p < 16; ++p)
      B2[(size_t)(p * 256 + t) * 32 + col] = SCALING * buf[p * 256 + t];
  }
}

// ===========================================================================
// Kernel 2: W'[n][k] = (codes-8)*scale + sum_r B2[n][r]*A2[r][k], bf16 out.
// ===========================================================================
__global__ __launch_bounds__(256) void k_wprime(const int* __restrict__ codes,
                                                const float* __restrict__ scales,
                                                const float* __restrict__ A2,
                                                const float* __restrict__ B2,
                                                u16* __restrict__ Wq) {
  __shared__ float A2s[32][128];
  __shared__ float B2t[32][128];
  const int t = threadIdx.x;
  const int n0 = (blockIdx.x >> 5) << 7;
  const int k0 = (blockIdx.x & 31) << 7;

#pragma unroll
  for (int q = 0; q < 4; ++q) {
    int f = (q * 256 + t) * 4;
    int r = f >> 7, c = f & 127;
    *(f32x4*)&A2s[r][c] = *(const f32x4*)(A2 + (size_t)r * 4096 + k0 + c);
  }
#pragma unroll
  for (int q = 0; q < 4; ++q) {
    int f = (q * 256 + t) * 4;
    int i = f >> 5, r = f & 31;
    f32x4 v = *(const f32x4*)(B2 + (size_t)(n0 + i) * 32 + r);
    B2t[r][i] = v[0]; B2t[r + 1][i] = v[1]; B2t[r + 2][i] = v[2]; B2t[r + 3][i] = v[3];
  }
  __syncthreads();

  const int tr = t >> 4, tc = t & 15;
  const int kg = k0 + tc * 8;
  float acc[8][8];
#pragma unroll
  for (int i = 0; i < 8; ++i) {
    const int n = n0 + tr * 8 + i;
    const float sc = scales[((size_t)n << 6) + (kg >> 6)];
    const i32x4 c0 = *(const i32x4*)(codes + (size_t)n * 4096 + kg);
    const i32x4 c1 = *(const i32x4*)(codes + (size_t)n * 4096 + kg + 4);
#pragma unroll
    for (int e = 0; e < 4; ++e) {
      acc[i][e]     = (float)(c0[e] - 8) * sc;
      acc[i][4 + e] = (float)(c1[e] - 8) * sc;
    }
  }
#pragma unroll
  for (int r = 0; r < 32; ++r) {
    const f32x4 a0 = *(const f32x4*)&A2s[r][tc * 8];
    const f32x4 a1 = *(const f32x4*)&A2s[r][tc * 8 + 4];
    const f32x4 b0 = *(const f32x4*)&B2t[r][tr * 8];
    const f32x4 b1 = *(const f32x4*)&B2t[r][tr * 8 + 4];
#pragma unroll
    for (int i = 0; i < 4; ++i) {
#pragma unroll
      for (int e = 0; e < 4; ++e) {
        acc[i][e]         += b0[i] * a0[e];
        acc[i][4 + e]     += b0[i] * a1[e];
        acc[4 + i][e]     += b1[i] * a0[e];
        acc[4 + i][4 + e] += b1[i] * a1[e];
      }
    }
  }
#pragma unroll
  for (int i = 0; i < 8; ++i) {
    const int n = n0 + tr * 8 + i;
    s16x8 o;
#pragma unroll
    for (int e = 0; e < 8; ++e) o[e] = (short)f2bf(acc[i][e]);
    *(s16x8*)(Wq + (size_t)n * 4096 + kg) = o;
  }
}

// ===========================================================================
// Main GEMM, 256x256 tile, BK=64, 4-segment schedule (R5 order, 1/4 barriers).
// Segment layout per iter (buf0=K(2it) segs 1-2, buf1=K(2it+1) segs 3-4):
//   seg1: read a0,b0,b1(buf0); S1 buf1.B0(k+1), S2 buf1.A1(k+1);
//         mma(0,0)+(0,1); VMC(8); BAR
//   seg2: read a1(buf0); S3 buf0.A0(k+2), S4 buf0.B1(k+2);
//         mma(1,1)+(1,0); VMC(6); BAR
//   seg3: read a0,b0,b1(buf1); S5 buf0.B0(k+2), S6 buf0.A1(k+2);
//         mma(0,0)+(0,1); VMC(8); BAR
//   seg4: read a1(buf1); S7 buf1.A0(k+3), S8 buf1.B1(k+3);
//         mma(1,1)+(1,0); VMC(6); BAR
// Queue-sim (2 ops/stage): VMC(8)@seg1 completes prev S6 (buf0.A1 before seg2
// read); VMC(6)@seg2 completes prev S7,S8 + S1 (buf1 full before seg3);
// VMC(8)@seg3 completes S2 (buf1.A1 before seg4); VMC(6)@seg4 completes
// S3,S4,S5 (buf0 full before next seg1). Stage-after-last-read separated by
// >=1 barrier in all 8 cases (b0/b1 kept in regs through each half).
// ===========================================================================
#define BAR()    __builtin_amdgcn_s_barrier()
#define VMC(n)   do { asm volatile("s_waitcnt vmcnt(" #n ")" ::: "memory"); \
                      __builtin_amdgcn_sched_barrier(0); } while (0)

template <int QM>
__device__ __forceinline__ void load_a(s16x8 a[4][2], const u16* as, int wm, int lane) {
  const int rl = lane & 15, sl = lane >> 4;
#pragma unroll
  for (int i = 0; i < 4; ++i) {
    const int row = QM * 128 + wm + i * 16 + rl;
#pragma unroll
    for (int kk = 0; kk < 2; ++kk) {
      const int slot = kk * 4 + sl;
      a[i][kk] = *(const s16x8*)(as + row * 64 + ((slot ^ (row & 7)) << 3));
    }
  }
}

template <int QN>
__device__ __forceinline__ void load_b(s16x8 b[2][2], const u16* bs, int wn, int lane) {
  const int rl = lane & 15, sl = lane >> 4;
#pragma unroll
  for (int j = 0; j < 2; ++j) {
    const int row = QN * 128 + wn + j * 16 + rl;
#pragma unroll
    for (int kk = 0; kk < 2; ++kk) {
      const int slot = kk * 4 + sl;
      b[j][kk] = *(const s16x8*)(bs + row * 64 + ((slot ^ (row & 7)) << 3));
    }
  }
}

template <int QM, int QN>
__device__ __forceinline__ void mma16(f32x4 acc[8][4], s16x8 a[4][2], s16x8 b[2][2]) {
  __builtin_amdgcn_s_setprio(1);
#pragma unroll
  for (int kk = 0; kk < 2; ++kk)
#pragma unroll
    for (int i = 0; i < 4; ++i)
#pragma unroll
      for (int j = 0; j < 2; ++j)
        acc[QM * 4 + i][QN * 2 + j] = mfma_bf16(a[i][kk], b[j][kk], acc[QM * 4 + i][QN * 2 + j]);
  __builtin_amdgcn_s_setprio(0);
}

__global__ __launch_bounds__(512, 2) void k_gemm8(const u16* __restrict__ Abf,
                                                  const u16* __restrict__ Bbf,
                                                  const float* __restrict__ bias,
                                                  float* __restrict__ out) {
  __shared__ __align__(16) u16 As[2][256 * 64];
  __shared__ __align__(16) u16 Bs[2][256 * 64];

  const int bid = blockIdx.x;
  const int wg = (bid & 7) * 64 + (bid >> 3);   // 512 % 8 == 0: bijective XCD swizzle
  const int mt = wg >> 4, nt = wg & 15;
  const int m0 = mt << 8, n0 = nt << 8;
  const int tid = threadIdx.x;
  const int lane = tid & 63;
  const int wid = tid >> 6;
  const int wm = (wid >> 2) * 64;   // row sub-offset within each 128-row half
  const int wn = (wid & 3) * 32;    // col sub-offset within each 128-col half

  int rowc[2], swzc[2];
#pragma unroll
  for (int c = 0; c < 2; ++c) {
    const int flat = (c * 512 + tid) * 8;
    rowc[c] = flat >> 6;
    const int slot = (flat >> 3) & 7;
    swzc[c] = (slot ^ (rowc[c] & 7)) << 3;   // inverse-swizzled global source
  }
  const u16* Ap0 = Abf + ((size_t)m0) * 4096;
  const u16* Ap1 = Abf + ((size_t)(m0 + 128)) * 4096;
  const u16* Bp0 = Bbf + ((size_t)n0) * 4096;
  const u16* Bp1 = Bbf + ((size_t)(n0 + 128)) * 4096;

#define STAGE(gpan, kt, ldsbase)                                              \
  do {                                                                        \
    _Pragma("unroll")                                                         \
    for (int c = 0; c < 2; ++c)                                               \
      gload_lds16((gpan) + (size_t)rowc[c] * 4096 + (kt) * 64 + swzc[c],      \
                  (ldsbase) + (c * 512 + tid) * 8);                           \
  } while (0)

  f32x4 acc[8][4] = {};
  s16x8 a[4][2], b0[2][2], b1[2][2];

  // ---- prologue: K0 full -> buf0; K1.A0 -> buf1.A0; K1.B1 -> buf1.B1 ----
  STAGE(Ap0, 0, As[0]);
  STAGE(Ap1, 0, As[0] + 8192);
  STAGE(Bp0, 0, Bs[0]);
  STAGE(Bp1, 0, Bs[0] + 8192);
  STAGE(Ap0, 1, As[1]);
  STAGE(Bp1, 1, Bs[1] + 8192);
  VMC(4);          // buf0 (8 ops) landed; buf1.A0/B1 may remain in flight
  BAR();

#pragma unroll 1
  for (int it = 0; it < 32; ++it) {
    const int kn1 = 2 * it + 1;
    const int ktA = (2 * it + 2 < 64) ? 2 * it + 2 : 63;  // clamped tail (dead stages)
    const int ktB = (2 * it + 3 < 64) ? 2 * it + 3 : 63;

    // ---- seg1: reads a0,b0,b1 (buf0); S1 buf1.B0; S2 buf1.A1; 32 MFMA ----
    load_a<0>(a, As[0], wm, lane);
    load_b<0>(b0, Bs[0], wn, lane);
    load_b<1>(b1, Bs[0], wn, lane);
    STAGE(Bp0, kn1, Bs[1]);
    STAGE(Ap1, kn1, As[1] + 8192);
    mma16<0, 0>(acc, a, b0);
    mma16<0, 1>(acc, a, b1);
    VMC(8);
    BAR();
    // ---- seg2: reads a1 (buf0); S3 buf0.A0; S4 buf0.B1; 32 MFMA ----
    load_a<1>(a, As[0], wm, lane);
    STAGE(Ap0, ktA, As[0]);
    STAGE(Bp1, ktA, Bs[0] + 8192);
    mma16<1, 1>(acc, a, b1);
    mma16<1, 0>(acc, a, b0);
    VMC(6);
    BAR();
    // ---- seg3: reads a0,b0,b1 (buf1); S5 buf0.B0; S6 buf0.A1; 32 MFMA ----
    load_a<0>(a, As[1], wm, lane);
    load_b<0>(b0, Bs[1], wn, lane);
    load_b<1>(b1, Bs[1], wn, lane);
    STAGE(Bp0, ktA, Bs[0]);
    STAGE(Ap1, ktA, As[0] + 8192);
    mma16<0, 0>(acc, a, b0);
    mma16<0, 1>(acc, a, b1);
    VMC(8);
    BAR();
    // ---- seg4: reads a1 (buf1); S7 buf1.A0; S8 buf1.B1; 32 MFMA ----
    load_a<1>(a, As[1], wm, lane);
    STAGE(Ap0, ktB, As[1]);
    STAGE(Bp1, ktB, Bs[1] + 8192);
    mma16<1, 1>(acc, a, b1);
    mma16<1, 0>(acc, a, b0);
    VMC(6);
    BAR();
  }

  // ---- epilogue: C/D layout col = lane&15, row = (lane>>4)*4 + v ----
  const int rl = lane & 15, rg = lane >> 4;
  float bv[4];
#pragma unroll
  for (int j = 0; j < 4; ++j)
    bv[j] = bias[n0 + (j >> 1) * 128 + wn + (j & 1) * 16 + rl];
#pragma unroll
  for (int i = 0; i < 8; ++i) {
    const int row0 = m0 + (i >> 2) * 128 + wm + (i & 3) * 16 + rg * 4;
#pragma unroll
    for (int j = 0; j < 4; ++j) {
      const int col = n0 + (j >> 1) * 128 + wn + (j & 1) * 16 + rl;
#pragma unroll
      for (int v = 0; v < 4; ++v)
        out[(size_t)(row0 + v) * 4096 + col] = acc[i][j][v] + bv[j];
    }
  }
#undef STAGE
}

// ===========================================================================
extern "C" void kernel_launch(void* const* d_in, const int* in_sizes, int n_in,
                              void* d_out, int out_size, void* d_ws, size_t ws_size,
                              hipStream_t stream) {
  const float* x      = (const float*)d_in[0];
  const int*   codes  = (const int*)d_in[1];
  const float* scales = (const float*)d_in[2];
  const float* th_v   = (const float*)d_in[3];
  const float* th_u   = (const float*)d_in[4];
  const float* lA     = (const float*)d_in[5];
  const float* lB     = (const float*)d_in[6];
  const float* bias   = (const float*)d_in[7];
  float* out = (float*)d_out;

  char* ws = (char*)d_ws;
  float* A2 = (float*)ws;                              // 512 KB
  float* B2 = (float*)(ws + (512u << 10));             // 512 KB
  u16*   Wq = (u16*)(ws + (1u << 20));                 // 32 MB
  u16*   xb = (u16*)(ws + (1u << 20) + (32u << 20));   // 64 MB

  k_prep<<<2112, 256, 0, stream>>>(lA, th_v, lB, th_u, x, A2, B2, xb);
  k_wprime<<<1024, 256, 0, stream>>>(codes, scales, A2, B2, Wq);
  k_gemm8<<<512, 512, 0, stream>>>(xb, Wq, bias, out);
}

// Round 12
// 329.525 us; speedup vs baseline: 1.1584x; 1.0256x over previous
//
#include <hip/hip_runtime.h>
#include <cstdint>
#include <type_traits>
#include <utility>

// ---------------------------------------------------------------------------
// SOARALinearLayer: out = x @ (W_deq + B2@A2)^T + bias
//   A2 = lora_A @ R_v, B2 = R_u @ lora_B (butterflies folded into LoRA factors)
// => one bf16 MFMA GEMM (M=8192, N=4096, K=4096) + tiny prep.
// R12: fragment pipelining — each segment's ds_reads hoisted to the END of
// the previous segment (after its counted VMC, before the barrier). Reads
// drain during barrier-wait + other waves' MFMA tails instead of stalling
// all waves post-barrier. VMEM issue order + VMC positions identical to R11
// (queue-sim re-verified with hoisted read positions); same registers reused.
// ---------------------------------------------------------------------------

typedef unsigned short u16;
typedef unsigned int   u32;
typedef short  s16x8 __attribute__((ext_vector_type(8)));
typedef __bf16 b16x8 __attribute__((ext_vector_type(8)));
typedef float  f32x4 __attribute__((ext_vector_type(4)));
typedef int    i32x4 __attribute__((ext_vector_type(4)));

#define SCALING 1.0f   /* ALPHA/RANK = 32/32 */

__device__ __forceinline__ u16 f2bf(float f) {
  u32 u = __builtin_bit_cast(u32, f);
  u += 0x7FFFu + ((u >> 16) & 1u);
  return (u16)(u >> 16);
}

template <typename T, typename = void>
struct mfma_takes_i16 : std::false_type {};
template <typename T>
struct mfma_takes_i16<T, std::void_t<decltype(__builtin_amdgcn_mfma_f32_16x16x32_bf16(
    std::declval<T>(), std::declval<T>(), std::declval<f32x4>(), 0, 0, 0))>>
    : std::true_type {};

template <typename T>
__device__ __forceinline__ f32x4 mfma_bf16(T a, T b, f32x4 c) {
  if constexpr (mfma_takes_i16<T>::value) {
    return __builtin_amdgcn_mfma_f32_16x16x32_bf16(a, b, c, 0, 0, 0);
  } else {
    return __builtin_amdgcn_mfma_f32_16x16x32_bf16(
        __builtin_bit_cast(b16x8, a), __builtin_bit_cast(b16x8, b), c, 0, 0, 0);
  }
}

__device__ __forceinline__ void gload_lds16(const void* g, void* l) {
  __builtin_amdgcn_global_load_lds((const __attribute__((address_space(1))) u32*)g,
                                   (__attribute__((address_space(3))) u32*)l,
                                   16, 0, 0);
}

// ===========================================================================
// Kernel 1 (merged prep): blocks 0-31: A2 = lora_A @ R_v (row rotations);
// blocks 32-63: B2 = R_u @ lora_B (col rotations); blocks 64..2111: x->bf16.
// ===========================================================================
__global__ __launch_bounds__(256) void k_prep(const float* __restrict__ A,
                                              const float* __restrict__ thA,
                                              const float* __restrict__ B,
                                              const float* __restrict__ thB,
                                              const float* __restrict__ x,
                                              float* __restrict__ A2,
                                              float* __restrict__ B2,
                                              u16* __restrict__ xb) {
  const int t = threadIdx.x;
  if (blockIdx.x >= 64) {
    const size_t stride = (size_t)2048 * 256 * 8;
    size_t i = ((size_t)(blockIdx.x - 64) * 256 + t) * 8;
#pragma unroll
    for (int it = 0; it < 8; ++it, i += stride) {
      f32x4 a = *(const f32x4*)(x + i);
      f32x4 b = *(const f32x4*)(x + i + 4);
      s16x8 o;
      o[0] = (short)f2bf(a[0]); o[1] = (short)f2bf(a[1]);
      o[2] = (short)f2bf(a[2]); o[3] = (short)f2bf(a[3]);
      o[4] = (short)f2bf(b[0]); o[5] = (short)f2bf(b[1]);
      o[6] = (short)f2bf(b[2]); o[7] = (short)f2bf(b[3]);
      *(s16x8*)(xb + i) = o;
    }
    return;
  }
  __shared__ float buf[4096];
  if (blockIdx.x < 32) {
    const int row = blockIdx.x;
    const float* src = A + (size_t)row * 4096;
    for (int p = 0; p < 16; ++p) buf[p * 256 + t] = src[p * 256 + t];
    __syncthreads();
    for (int j = 0; j < 12; ++j) {
      const int k = 4096 >> j;
      const int half = k >> 1;
      const int lh = 11 - j;
      for (int p = 0; p < 8; ++p) {
        int tp = p * 256 + t;
        int b = tp >> lh;
        int i = tp & (half - 1);
        int pi = b * k + i;
        int qi = pi + half;
        float s, c;
        sincosf(thA[j * 2048 + tp], &s, &c);
        float xp = buf[pi], xq = buf[qi];
        buf[pi] = c * xp + s * xq;
        buf[qi] = -s * xp + c * xq;
      }
      __syncthreads();
    }
    for (int p = 0; p < 16; ++p) A2[(size_t)row * 4096 + p * 256 + t] = buf[p * 256 + t];
  } else {
    const int col = blockIdx.x - 32;
    for (int p = 0; p < 16; ++p) buf[p * 256 + t] = B[(size_t)(p * 256 + t) * 32 + col];
    __syncthreads();
    for (int j = 11; j >= 0; --j) {
      const int k = 4096 >> j;
      const int half = k >> 1;
      const int lh = 11 - j;
      for (int p = 0; p < 8; ++p) {
        int tp = p * 256 + t;
        int b = tp >> lh;
        int i = tp & (half - 1);
        int pi = b * k + i;
        int qi = pi + half;
        float s, c;
        sincosf(thB[j * 2048 + tp], &s, &c);
        float xp = buf[pi], xq = buf[qi];
        buf[pi] = c * xp - s * xq;
        buf[qi] = s * xp + c * xq;
      }
      __syncthreads();
    }
    for (int p = 0; p < 16; ++p)
      B2[(size_t)(p * 256 + t) * 32 + col] = SCALING * buf[p * 256 + t];
  }
}

// ===========================================================================
// Kernel 2: W'[n][k] = (codes-8)*scale + sum_r B2[n][r]*A2[r][k], bf16 out.
// ===========================================================================
__global__ __launch_bounds__(256) void k_wprime(const int* __restrict__ codes,
                                                const float* __restrict__ scales,
                                                const float* __restrict__ A2,
                                                const float* __restrict__ B2,
                                                u16* __restrict__ Wq) {
  __shared__ float A2s[32][128];
  __shared__ float B2t[32][128];
  const int t = threadIdx.x;
  const int n0 = (blockIdx.x >> 5) << 7;
  const int k0 = (blockIdx.x & 31) << 7;

#pragma unroll
  for (int q = 0; q < 4; ++q) {
    int f = (q * 256 + t) * 4;
    int r = f >> 7, c = f & 127;
    *(f32x4*)&A2s[r][c] = *(const f32x4*)(A2 + (size_t)r * 4096 + k0 + c);
  }
#pragma unroll
  for (int q = 0; q < 4; ++q) {
    int f = (q * 256 + t) * 4;
    int i = f >> 5, r = f & 31;
    f32x4 v = *(const f32x4*)(B2 + (size_t)(n0 + i) * 32 + r);
    B2t[r][i] = v[0]; B2t[r + 1][i] = v[1]; B2t[r + 2][i] = v[2]; B2t[r + 3][i] = v[3];
  }
  __syncthreads();

  const int tr = t >> 4, tc = t & 15;
  const int kg = k0 + tc * 8;
  float acc[8][8];
#pragma unroll
  for (int i = 0; i < 8; ++i) {
    const int n = n0 + tr * 8 + i;
    const float sc = scales[((size_t)n << 6) + (kg >> 6)];
    const i32x4 c0 = *(const i32x4*)(codes + (size_t)n * 4096 + kg);
    const i32x4 c1 = *(const i32x4*)(codes + (size_t)n * 4096 + kg + 4);
#pragma unroll
    for (int e = 0; e < 4; ++e) {
      acc[i][e]     = (float)(c0[e] - 8) * sc;
      acc[i][4 + e] = (float)(c1[e] - 8) * sc;
    }
  }
#pragma unroll
  for (int r = 0; r < 32; ++r) {
    const f32x4 a0 = *(const f32x4*)&A2s[r][tc * 8];
    const f32x4 a1 = *(const f32x4*)&A2s[r][tc * 8 + 4];
    const f32x4 b0 = *(const f32x4*)&B2t[r][tr * 8];
    const f32x4 b1 = *(const f32x4*)&B2t[r][tr * 8 + 4];
#pragma unroll
    for (int i = 0; i < 4; ++i) {
#pragma unroll
      for (int e = 0; e < 4; ++e) {
        acc[i][e]         += b0[i] * a0[e];
        acc[i][4 + e]     += b0[i] * a1[e];
        acc[4 + i][e]     += b1[i] * a0[e];
        acc[4 + i][4 + e] += b1[i] * a1[e];
      }
    }
  }
#pragma unroll
  for (int i = 0; i < 8; ++i) {
    const int n = n0 + tr * 8 + i;
    s16x8 o;
#pragma unroll
    for (int e = 0; e < 8; ++e) o[e] = (short)f2bf(acc[i][e]);
    *(s16x8*)(Wq + (size_t)n * 4096 + kg) = o;
  }
}

// ===========================================================================
// Main GEMM, 256x256 tile, BK=64, 4 segments/iter, fragment-pipelined reads.
// Per segment: [STAGEs] [MFMA on regs loaded last segment] [counted VMC]
// [ds_reads for NEXT segment] [BAR]. VMEM order/waits identical to R11:
//   seg1: S1 buf1.B0(k+1), S2 buf1.A1(k+1); VMC(8) -> drains prev S6
//         (buf0.A1) -> load a1(buf0) for seg2.
//   seg2: S3 buf0.A0(k+2), S4 buf0.B1(k+2); VMC(6) -> drains S7,S8,S1
//         (buf1.A0/B1/B0) -> load a0,b0,b1(buf1) for seg3.
//   seg3: S5 buf0.B0(k+2), S6 buf0.A1(k+2); VMC(8) -> drains S2 (buf1.A1)
//         -> load a1(buf1) for seg4.
//   seg4: S7 buf1.A0(k+3), S8 buf1.B1(k+3); VMC(6) -> drains S3,S4,S5
//         (buf0 full, K+2) -> load a0,b0,b1(buf0) for next seg1.
// WAR: every stage lands >=1 barrier after its region's last (hoisted) read.
// ===========================================================================
#define BAR()    __builtin_amdgcn_s_barrier()
#define VMC(n)   do { asm volatile("s_waitcnt vmcnt(" #n ")" ::: "memory"); \
                      __builtin_amdgcn_sched_barrier(0); } while (0)

template <int QM>
__device__ __forceinline__ void load_a(s16x8 a[4][2], const u16* as, int wm, int lane) {
  const int rl = lane & 15, sl = lane >> 4;
#pragma unroll
  for (int i = 0; i < 4; ++i) {
    const int row = QM * 128 + wm + i * 16 + rl;
#pragma unroll
    for (int kk = 0; kk < 2; ++kk) {
      const int slot = kk * 4 + sl;
      a[i][kk] = *(const s16x8*)(as + row * 64 + ((slot ^ (row & 7)) << 3));
    }
  }
}

template <int QN>
__device__ __forceinline__ void load_b(s16x8 b[2][2], const u16* bs, int wn, int lane) {
  const int rl = lane & 15, sl = lane >> 4;
#pragma unroll
  for (int j = 0; j < 2; ++j) {
    const int row = QN * 128 + wn + j * 16 + rl;
#pragma unroll
    for (int kk = 0; kk < 2; ++kk) {
      const int slot = kk * 4 + sl;
      b[j][kk] = *(const s16x8*)(bs + row * 64 + ((slot ^ (row & 7)) << 3));
    }
  }
}

template <int QM, int QN>
__device__ __forceinline__ void mma16(f32x4 acc[8][4], s16x8 a[4][2], s16x8 b[2][2]) {
  __builtin_amdgcn_s_setprio(1);
#pragma unroll
  for (int kk = 0; kk < 2; ++kk)
#pragma unroll
    for (int i = 0; i < 4; ++i)
#pragma unroll
      for (int j = 0; j < 2; ++j)
        acc[QM * 4 + i][QN * 2 + j] = mfma_bf16(a[i][kk], b[j][kk], acc[QM * 4 + i][QN * 2 + j]);
  __builtin_amdgcn_s_setprio(0);
}

__global__ __launch_bounds__(512, 2) void k_gemm8(const u16* __restrict__ Abf,
                                                  const u16* __restrict__ Bbf,
                                                  const float* __restrict__ bias,
                                                  float* __restrict__ out) {
  __shared__ __align__(16) u16 As[2][256 * 64];
  __shared__ __align__(16) u16 Bs[2][256 * 64];

  const int bid = blockIdx.x;
  const int wg = (bid & 7) * 64 + (bid >> 3);   // 512 % 8 == 0: bijective XCD swizzle
  const int mt = wg >> 4, nt = wg & 15;
  const int m0 = mt << 8, n0 = nt << 8;
  const int tid = threadIdx.x;
  const int lane = tid & 63;
  const int wid = tid >> 6;
  const int wm = (wid >> 2) * 64;   // row sub-offset within each 128-row half
  const int wn = (wid & 3) * 32;    // col sub-offset within each 128-col half

  int rowc[2], swzc[2];
#pragma unroll
  for (int c = 0; c < 2; ++c) {
    const int flat = (c * 512 + tid) * 8;
    rowc[c] = flat >> 6;
    const int slot = (flat >> 3) & 7;
    swzc[c] = (slot ^ (rowc[c] & 7)) << 3;   // inverse-swizzled global source
  }
  const u16* Ap0 = Abf + ((size_t)m0) * 4096;
  const u16* Ap1 = Abf + ((size_t)(m0 + 128)) * 4096;
  const u16* Bp0 = Bbf + ((size_t)n0) * 4096;
  const u16* Bp1 = Bbf + ((size_t)(n0 + 128)) * 4096;

#define STAGE(gpan, kt, ldsbase)                                              \
  do {                                                                        \
    _Pragma("unroll")                                                         \
    for (int c = 0; c < 2; ++c)                                               \
      gload_lds16((gpan) + (size_t)rowc[c] * 4096 + (kt) * 64 + swzc[c],      \
                  (ldsbase) + (c * 512 + tid) * 8);                           \
  } while (0)

  f32x4 acc[8][4] = {};
  s16x8 a[4][2], b0[2][2], b1[2][2];

  // ---- prologue: K0 full -> buf0; K1.A0 -> buf1.A0; K1.B1 -> buf1.B1 ----
  STAGE(Ap0, 0, As[0]);
  STAGE(Ap1, 0, As[0] + 8192);
  STAGE(Bp0, 0, Bs[0]);
  STAGE(Bp1, 0, Bs[0] + 8192);
  STAGE(Ap0, 1, As[1]);
  STAGE(Bp1, 1, Bs[1] + 8192);
  VMC(4);          // buf0 (8 ops) landed; buf1.A0/B1 may remain in flight
  BAR();
  // pre-load seg1 fragments (buf0, valid after VMC(4))
  load_a<0>(a, As[0], wm, lane);
  load_b<0>(b0, Bs[0], wn, lane);
  load_b<1>(b1, Bs[0], wn, lane);

#pragma unroll 1
  for (int it = 0; it < 32; ++it) {
    const int kn1 = 2 * it + 1;
    const int ktA = (2 * it + 2 < 64) ? 2 * it + 2 : 63;  // clamped tail (dead stages)
    const int ktB = (2 * it + 3 < 64) ? 2 * it + 3 : 63;

    // ---- seg1: S1 buf1.B0; S2 buf1.A1; mma(0,0)+(0,1); VMC(8); read a1(buf0) ----
    STAGE(Bp0, kn1, Bs[1]);
    STAGE(Ap1, kn1, As[1] + 8192);
    mma16<0, 0>(acc, a, b0);
    mma16<0, 1>(acc, a, b1);
    VMC(8);
    load_a<1>(a, As[0], wm, lane);          // buf0.A1 (prev S6, drained)
    BAR();
    // ---- seg2: S3 buf0.A0; S4 buf0.B1; mma(1,1)+(1,0); VMC(6); read buf1 frags ----
    STAGE(Ap0, ktA, As[0]);
    STAGE(Bp1, ktA, Bs[0] + 8192);
    mma16<1, 1>(acc, a, b1);
    mma16<1, 0>(acc, a, b0);
    VMC(6);
    load_a<0>(a, As[1], wm, lane);          // buf1.A0 (S7p/P5 or S7, drained)
    load_b<0>(b0, Bs[1], wn, lane);         // buf1.B0 (S1, drained)
    load_b<1>(b1, Bs[1], wn, lane);         // buf1.B1 (S8p/P6, drained)
    BAR();
    // ---- seg3: S5 buf0.B0; S6 buf0.A1; mma(0,0)+(0,1); VMC(8); read a1(buf1) ----
    STAGE(Bp0, ktA, Bs[0]);
    STAGE(Ap1, ktA, As[0] + 8192);
    mma16<0, 0>(acc, a, b0);
    mma16<0, 1>(acc, a, b1);
    VMC(8);
    load_a<1>(a, As[1], wm, lane);          // buf1.A1 (S2, drained)
    BAR();
    // ---- seg4: S7 buf1.A0; S8 buf1.B1; mma(1,1)+(1,0); VMC(6); read buf0 frags ----
    STAGE(Ap0, ktB, As[1]);
    STAGE(Bp1, ktB, Bs[1] + 8192);
    mma16<1, 1>(acc, a, b1);
    mma16<1, 0>(acc, a, b0);
    VMC(6);
    load_a<0>(a, As[0], wm, lane);          // buf0.A0 next K (S3, drained)
    load_b<0>(b0, Bs[0], wn, lane);         // buf0.B0 (S5, drained)
    load_b<1>(b1, Bs[0], wn, lane);         // buf0.B1 (S4, drained)
    BAR();
  }

  // ---- epilogue: C/D layout col = lane&15, row = (lane>>4)*4 + v ----
  const int rl = lane & 15, rg = lane >> 4;
  float bv[4];
#pragma unroll
  for (int j = 0; j < 4; ++j)
    bv[j] = bias[n0 + (j >> 1) * 128 + wn + (j & 1) * 16 + rl];
#pragma unroll
  for (int i = 0; i < 8; ++i) {
    const int row0 = m0 + (i >> 2) * 128 + wm + (i & 3) * 16 + rg * 4;
#pragma unroll
    for (int j = 0; j < 4; ++j) {
      const int col = n0 + (j >> 1) * 128 + wn + (j & 1) * 16 + rl;
#pragma unroll
      for (int v = 0; v < 4; ++v)
        out[(size_t)(row0 + v) * 4096 + col] = acc[i][j][v] + bv[j];
    }
  }
#undef STAGE
}

// ===========================================================================
extern "C" void kernel_launch(void* const* d_in, const int* in_sizes, int n_in,
                              void* d_out, int out_size, void* d_ws, size_t ws_size,
                              hipStream_t stream) {
  const float* x      = (const float*)d_in[0];
  const int*   codes  = (const int*)d_in[1];
  const float* scales = (const float*)d_in[2];
  const float* th_v   = (const float*)d_in[3];
  const float* th_u   = (const float*)d_in[4];
  const float* lA     = (const float*)d_in[5];
  const float* lB     = (const float*)d_in[6];
  const float* bias   = (const float*)d_in[7];
  float* out = (float*)d_out;

  char* ws = (char*)d_ws;
  float* A2 = (float*)ws;                              // 512 KB
  float* B2 = (float*)(ws + (512u << 10));             // 512 KB
  u16*   Wq = (u16*)(ws + (1u << 20));                 // 32 MB
  u16*   xb = (u16*)(ws + (1u << 20) + (32u << 20));   // 64 MB

  k_prep<<<2112, 256, 0, stream>>>(lA, th_v, lB, th_u, x, A2, B2, xb);
  k_wprime<<<1024, 256, 0, stream>>>(codes, scales, A2, B2, Wq);
  k_gemm8<<<512, 512, 0, stream>>>(xb, Wq, bias, out);
}

// Round 14
// 296.578 us; speedup vs baseline: 1.2871x; 1.1111x over previous
//
#include <hip/hip_runtime.h>
#include <cstdint>
#include <type_traits>
#include <utility>

// ---------------------------------------------------------------------------
// SOARALinearLayer: out = x @ (W_deq + B2@A2)^T + bias
//   A2 = lora_A @ R_v, B2 = R_u @ lora_B (butterflies folded into LoRA factors)
// => one bf16 MFMA GEMM (M=8192, N=4096, K=4096) + tiny prep.
// R13: prep restructure. k_rot alone (64 blocks, __sincosf); then k_fused =
// wprime (blocks 0-1023) || x->bf16 (blocks 1024-3071) so the rot tail no
// longer gates the streaming work. GEMM = exact R12 champion (248us).
// ---------------------------------------------------------------------------

typedef unsigned short u16;
typedef unsigned int   u32;
typedef short  s16x8 __attribute__((ext_vector_type(8)));
typedef __bf16 b16x8 __attribute__((ext_vector_type(8)));
typedef float  f32x4 __attribute__((ext_vector_type(4)));
typedef int    i32x4 __attribute__((ext_vector_type(4)));

#define SCALING 1.0f   /* ALPHA/RANK = 32/32 */

__device__ __forceinline__ u16 f2bf(float f) {
  u32 u = __builtin_bit_cast(u32, f);
  u += 0x7FFFu + ((u >> 16) & 1u);
  return (u16)(u >> 16);
}

template <typename T, typename = void>
struct mfma_takes_i16 : std::false_type {};
template <typename T>
struct mfma_takes_i16<T, std::void_t<decltype(__builtin_amdgcn_mfma_f32_16x16x32_bf16(
    std::declval<T>(), std::declval<T>(), std::declval<f32x4>(), 0, 0, 0))>>
    : std::true_type {};

template <typename T>
__device__ __forceinline__ f32x4 mfma_bf16(T a, T b, f32x4 c) {
  if constexpr (mfma_takes_i16<T>::value) {
    return __builtin_amdgcn_mfma_f32_16x16x32_bf16(a, b, c, 0, 0, 0);
  } else {
    return __builtin_amdgcn_mfma_f32_16x16x32_bf16(
        __builtin_bit_cast(b16x8, a), __builtin_bit_cast(b16x8, b), c, 0, 0, 0);
  }
}

__device__ __forceinline__ void gload_lds16(const void* g, void* l) {
  __builtin_amdgcn_global_load_lds((const __attribute__((address_space(1))) u32*)g,
                                   (__attribute__((address_space(3))) u32*)l,
                                   16, 0, 0);
}

// ===========================================================================
// Kernel 1: rotations only. blocks 0-31: A2 = lora_A @ R_v; 32-63: B2 = R_u@B.
// __sincosf: thetas ~N(0,0.02); ulp error << bf16 quantization downstream.
// ===========================================================================
__global__ __launch_bounds__(256) void k_rot(const float* __restrict__ A,
                                             const float* __restrict__ thA,
                                             const float* __restrict__ B,
                                             const float* __restrict__ thB,
                                             float* __restrict__ A2,
                                             float* __restrict__ B2) {
  __shared__ float buf[4096];
  const int t = threadIdx.x;
  if (blockIdx.x < 32) {
    const int row = blockIdx.x;
    const float* src = A + (size_t)row * 4096;
    for (int p = 0; p < 16; ++p) buf[p * 256 + t] = src[p * 256 + t];
    __syncthreads();
    for (int j = 0; j < 12; ++j) {
      const int k = 4096 >> j;
      const int half = k >> 1;
      const int lh = 11 - j;
      for (int p = 0; p < 8; ++p) {
        int tp = p * 256 + t;
        int b = tp >> lh;
        int i = tp & (half - 1);
        int pi = b * k + i;
        int qi = pi + half;
        float s, c;
        __sincosf(thA[j * 2048 + tp], &s, &c);
        float xp = buf[pi], xq = buf[qi];
        buf[pi] = c * xp + s * xq;
        buf[qi] = -s * xp + c * xq;
      }
      __syncthreads();
    }
    for (int p = 0; p < 16; ++p) A2[(size_t)row * 4096 + p * 256 + t] = buf[p * 256 + t];
  } else {
    const int col = blockIdx.x - 32;
    for (int p = 0; p < 16; ++p) buf[p * 256 + t] = B[(size_t)(p * 256 + t) * 32 + col];
    __syncthreads();
    for (int j = 11; j >= 0; --j) {
      const int k = 4096 >> j;
      const int half = k >> 1;
      const int lh = 11 - j;
      for (int p = 0; p < 8; ++p) {
        int tp = p * 256 + t;
        int b = tp >> lh;
        int i = tp & (half - 1);
        int pi = b * k + i;
        int qi = pi + half;
        float s, c;
        __sincosf(thB[j * 2048 + tp], &s, &c);
        float xp = buf[pi], xq = buf[qi];
        buf[pi] = c * xp - s * xq;
        buf[qi] = s * xp + c * xq;
      }
      __syncthreads();
    }
    for (int p = 0; p < 16; ++p)
      B2[(size_t)(p * 256 + t) * 32 + col] = SCALING * buf[p * 256 + t];
  }
}

// ===========================================================================
// Kernel 2 (fused): blocks 0-1023: W' build (needs A2/B2 from k_rot);
// blocks 1024-3071: x (f32) -> bf16 streaming. Disjoint outputs, race-free.
// ===========================================================================
__global__ __launch_bounds__(256) void k_fused(const int* __restrict__ codes,
                                               const float* __restrict__ scales,
                                               const float* __restrict__ A2,
                                               const float* __restrict__ B2,
                                               u16* __restrict__ Wq,
                                               const float* __restrict__ x,
                                               u16* __restrict__ xb) {
  const int t = threadIdx.x;
  if (blockIdx.x >= 1024) {
    // ---- x -> bf16: 2048 blocks x 8 iters x 8 elems x 256 thr = 32M elems ----
    const size_t stride = (size_t)2048 * 256 * 8;
    size_t i = ((size_t)(blockIdx.x - 1024) * 256 + t) * 8;
#pragma unroll
    for (int it = 0; it < 8; ++it, i += stride) {
      f32x4 a = *(const f32x4*)(x + i);
      f32x4 b = *(const f32x4*)(x + i + 4);
      s16x8 o;
      o[0] = (short)f2bf(a[0]); o[1] = (short)f2bf(a[1]);
      o[2] = (short)f2bf(a[2]); o[3] = (short)f2bf(a[3]);
      o[4] = (short)f2bf(b[0]); o[5] = (short)f2bf(b[1]);
      o[6] = (short)f2bf(b[2]); o[7] = (short)f2bf(b[3]);
      *(s16x8*)(xb + i) = o;
    }
    return;
  }
  // ---- W'[n][k] = (codes-8)*scale + sum_r B2[n][r]*A2[r][k], bf16 out ----
  __shared__ float A2s[32][128];
  __shared__ float B2t[32][128];
  const int n0 = (blockIdx.x >> 5) << 7;
  const int k0 = (blockIdx.x & 31) << 7;

#pragma unroll
  for (int q = 0; q < 4; ++q) {
    int f = (q * 256 + t) * 4;
    int r = f >> 7, c = f & 127;
    *(f32x4*)&A2s[r][c] = *(const f32x4*)(A2 + (size_t)r * 4096 + k0 + c);
  }
#pragma unroll
  for (int q = 0; q < 4; ++q) {
    int f = (q * 256 + t) * 4;
    int i = f >> 5, r = f & 31;
    f32x4 v = *(const f32x4*)(B2 + (size_t)(n0 + i) * 32 + r);
    B2t[r][i] = v[0]; B2t[r + 1][i] = v[1]; B2t[r + 2][i] = v[2]; B2t[r + 3][i] = v[3];
  }
  __syncthreads();

  const int tr = t >> 4, tc = t & 15;
  const int kg = k0 + tc * 8;
  float acc[8][8];
#pragma unroll
  for (int i = 0; i < 8; ++i) {
    const int n = n0 + tr * 8 + i;
    const float sc = scales[((size_t)n << 6) + (kg >> 6)];
    const i32x4 c0 = *(const i32x4*)(codes + (size_t)n * 4096 + kg);
    const i32x4 c1 = *(const i32x4*)(codes + (size_t)n * 4096 + kg + 4);
#pragma unroll
    for (int e = 0; e < 4; ++e) {
      acc[i][e]     = (float)(c0[e] - 8) * sc;
      acc[i][4 + e] = (float)(c1[e] - 8) * sc;
    }
  }
#pragma unroll
  for (int r = 0; r < 32; ++r) {
    const f32x4 a0 = *(const f32x4*)&A2s[r][tc * 8];
    const f32x4 a1 = *(const f32x4*)&A2s[r][tc * 8 + 4];
    const f32x4 b0 = *(const f32x4*)&B2t[r][tr * 8];
    const f32x4 b1 = *(const f32x4*)&B2t[r][tr * 8 + 4];
#pragma unroll
    for (int i = 0; i < 4; ++i) {
#pragma unroll
      for (int e = 0; e < 4; ++e) {
        acc[i][e]         += b0[i] * a0[e];
        acc[i][4 + e]     += b0[i] * a1[e];
        acc[4 + i][e]     += b1[i] * a0[e];
        acc[4 + i][4 + e] += b1[i] * a1[e];
      }
    }
  }
#pragma unroll
  for (int i = 0; i < 8; ++i) {
    const int n = n0 + tr * 8 + i;
    s16x8 o;
#pragma unroll
    for (int e = 0; e < 8; ++e) o[e] = (short)f2bf(acc[i][e]);
    *(s16x8*)(Wq + (size_t)n * 4096 + kg) = o;
  }
}

// ===========================================================================
// Main GEMM — EXACT R12 champion (248us): 256x256 tile, BK=64, 4 segments,
// fragment-pipelined reads (hoisted post-VMC, pre-barrier).
// ===========================================================================
#define BAR()    __builtin_amdgcn_s_barrier()
#define VMC(n)   do { asm volatile("s_waitcnt vmcnt(" #n ")" ::: "memory"); \
                      __builtin_amdgcn_sched_barrier(0); } while (0)

template <int QM>
__device__ __forceinline__ void load_a(s16x8 a[4][2], const u16* as, int wm, int lane) {
  const int rl = lane & 15, sl = lane >> 4;
#pragma unroll
  for (int i = 0; i < 4; ++i) {
    const int row = QM * 128 + wm + i * 16 + rl;
#pragma unroll
    for (int kk = 0; kk < 2; ++kk) {
      const int slot = kk * 4 + sl;
      a[i][kk] = *(const s16x8*)(as + row * 64 + ((slot ^ (row & 7)) << 3));
    }
  }
}

template <int QN>
__device__ __forceinline__ void load_b(s16x8 b[2][2], const u16* bs, int wn, int lane) {
  const int rl = lane & 15, sl = lane >> 4;
#pragma unroll
  for (int j = 0; j < 2; ++j) {
    const int row = QN * 128 + wn + j * 16 + rl;
#pragma unroll
    for (int kk = 0; kk < 2; ++kk) {
      const int slot = kk * 4 + sl;
      b[j][kk] = *(const s16x8*)(bs + row * 64 + ((slot ^ (row & 7)) << 3));
    }
  }
}

template <int QM, int QN>
__device__ __forceinline__ void mma16(f32x4 acc[8][4], s16x8 a[4][2], s16x8 b[2][2]) {
  __builtin_amdgcn_s_setprio(1);
#pragma unroll
  for (int kk = 0; kk < 2; ++kk)
#pragma unroll
    for (int i = 0; i < 4; ++i)
#pragma unroll
      for (int j = 0; j < 2; ++j)
        acc[QM * 4 + i][QN * 2 + j] = mfma_bf16(a[i][kk], b[j][kk], acc[QM * 4 + i][QN * 2 + j]);
  __builtin_amdgcn_s_setprio(0);
}

__global__ __launch_bounds__(512, 2) void k_gemm8(const u16* __restrict__ Abf,
                                                  const u16* __restrict__ Bbf,
                                                  const float* __restrict__ bias,
                                                  float* __restrict__ out) {
  __shared__ __align__(16) u16 As[2][256 * 64];
  __shared__ __align__(16) u16 Bs[2][256 * 64];

  const int bid = blockIdx.x;
  const int wg = (bid & 7) * 64 + (bid >> 3);   // 512 % 8 == 0: bijective XCD swizzle
  const int mt = wg >> 4, nt = wg & 15;
  const int m0 = mt << 8, n0 = nt << 8;
  const int tid = threadIdx.x;
  const int lane = tid & 63;
  const int wid = tid >> 6;
  const int wm = (wid >> 2) * 64;   // row sub-offset within each 128-row half
  const int wn = (wid & 3) * 32;    // col sub-offset within each 128-col half

  int rowc[2], swzc[2];
#pragma unroll
  for (int c = 0; c < 2; ++c) {
    const int flat = (c * 512 + tid) * 8;
    rowc[c] = flat >> 6;
    const int slot = (flat >> 3) & 7;
    swzc[c] = (slot ^ (rowc[c] & 7)) << 3;   // inverse-swizzled global source
  }
  const u16* Ap0 = Abf + ((size_t)m0) * 4096;
  const u16* Ap1 = Abf + ((size_t)(m0 + 128)) * 4096;
  const u16* Bp0 = Bbf + ((size_t)n0) * 4096;
  const u16* Bp1 = Bbf + ((size_t)(n0 + 128)) * 4096;

#define STAGE(gpan, kt, ldsbase)                                              \
  do {                                                                        \
    _Pragma("unroll")                                                         \
    for (int c = 0; c < 2; ++c)                                               \
      gload_lds16((gpan) + (size_t)rowc[c] * 4096 + (kt) * 64 + swzc[c],      \
                  (ldsbase) + (c * 512 + tid) * 8);                           \
  } while (0)

  f32x4 acc[8][4] = {};
  s16x8 a[4][2], b0[2][2], b1[2][2];

  // ---- prologue: K0 full -> buf0; K1.A0 -> buf1.A0; K1.B1 -> buf1.B1 ----
  STAGE(Ap0, 0, As[0]);
  STAGE(Ap1, 0, As[0] + 8192);
  STAGE(Bp0, 0, Bs[0]);
  STAGE(Bp1, 0, Bs[0] + 8192);
  STAGE(Ap0, 1, As[1]);
  STAGE(Bp1, 1, Bs[1] + 8192);
  VMC(4);          // buf0 (8 ops) landed; buf1.A0/B1 may remain in flight
  BAR();
  // pre-load seg1 fragments (buf0, valid after VMC(4))
  load_a<0>(a, As[0], wm, lane);
  load_b<0>(b0, Bs[0], wn, lane);
  load_b<1>(b1, Bs[0], wn, lane);

#pragma unroll 1
  for (int it = 0; it < 32; ++it) {
    const int kn1 = 2 * it + 1;
    const int ktA = (2 * it + 2 < 64) ? 2 * it + 2 : 63;  // clamped tail (dead stages)
    const int ktB = (2 * it + 3 < 64) ? 2 * it + 3 : 63;

    // ---- seg1: S1 buf1.B0; S2 buf1.A1; mma(0,0)+(0,1); VMC(8); read a1(buf0) ----
    STAGE(Bp0, kn1, Bs[1]);
    STAGE(Ap1, kn1, As[1] + 8192);
    mma16<0, 0>(acc, a, b0);
    mma16<0, 1>(acc, a, b1);
    VMC(8);
    load_a<1>(a, As[0], wm, lane);          // buf0.A1 (prev S6, drained)
    BAR();
    // ---- seg2: S3 buf0.A0; S4 buf0.B1; mma(1,1)+(1,0); VMC(6); read buf1 frags ----
    STAGE(Ap0, ktA, As[0]);
    STAGE(Bp1, ktA, Bs[0] + 8192);
    mma16<1, 1>(acc, a, b1);
    mma16<1, 0>(acc, a, b0);
    VMC(6);
    load_a<0>(a, As[1], wm, lane);          // buf1.A0 (drained)
    load_b<0>(b0, Bs[1], wn, lane);         // buf1.B0 (S1, drained)
    load_b<1>(b1, Bs[1], wn, lane);         // buf1.B1 (drained)
    BAR();
    // ---- seg3: S5 buf0.B0; S6 buf0.A1; mma(0,0)+(0,1); VMC(8); read a1(buf1) ----
    STAGE(Bp0, ktA, Bs[0]);
    STAGE(Ap1, ktA, As[0] + 8192);
    mma16<0, 0>(acc, a, b0);
    mma16<0, 1>(acc, a, b1);
    VMC(8);
    load_a<1>(a, As[1], wm, lane);          // buf1.A1 (S2, drained)
    BAR();
    // ---- seg4: S7 buf1.A0; S8 buf1.B1; mma(1,1)+(1,0); VMC(6); read buf0 frags ----
    STAGE(Ap0, ktB, As[1]);
    STAGE(Bp1, ktB, Bs[1] + 8192);
    mma16<1, 1>(acc, a, b1);
    mma16<1, 0>(acc, a, b0);
    VMC(6);
    load_a<0>(a, As[0], wm, lane);          // buf0.A0 next K (S3, drained)
    load_b<0>(b0, Bs[0], wn, lane);         // buf0.B0 (S5, drained)
    load_b<1>(b1, Bs[0], wn, lane);         // buf0.B1 (S4, drained)
    BAR();
  }

  // ---- epilogue: C/D layout col = lane&15, row = (lane>>4)*4 + v ----
  const int rl = lane & 15, rg = lane >> 4;
  float bv[4];
#pragma unroll
  for (int j = 0; j < 4; ++j)
    bv[j] = bias[n0 + (j >> 1) * 128 + wn + (j & 1) * 16 + rl];
#pragma unroll
  for (int i = 0; i < 8; ++i) {
    const int row0 = m0 + (i >> 2) * 128 + wm + (i & 3) * 16 + rg * 4;
#pragma unroll
    for (int j = 0; j < 4; ++j) {
      const int col = n0 + (j >> 1) * 128 + wn + (j & 1) * 16 + rl;
#pragma unroll
      for (int v = 0; v < 4; ++v)
        out[(size_t)(row0 + v) * 4096 + col] = acc[i][j][v] + bv[j];
    }
  }
#undef STAGE
}

// ===========================================================================
extern "C" void kernel_launch(void* const* d_in, const int* in_sizes, int n_in,
                              void* d_out, int out_size, void* d_ws, size_t ws_size,
                              hipStream_t stream) {
  const float* x      = (const float*)d_in[0];
  const int*   codes  = (const int*)d_in[1];
  const float* scales = (const float*)d_in[2];
  const float* th_v   = (const float*)d_in[3];
  const float* th_u   = (const float*)d_in[4];
  const float* lA     = (const float*)d_in[5];
  const float* lB     = (const float*)d_in[6];
  const float* bias   = (const float*)d_in[7];
  float* out = (float*)d_out;

  char* ws = (char*)d_ws;
  float* A2 = (float*)ws;                              // 512 KB
  float* B2 = (float*)(ws + (512u << 10));             // 512 KB
  u16*   Wq = (u16*)(ws + (1u << 20));                 // 32 MB
  u16*   xb = (u16*)(ws + (1u << 20) + (32u << 20));   // 64 MB

  k_rot<<<64, 256, 0, stream>>>(lA, th_v, lB, th_u, A2, B2);
  k_fused<<<3072, 256, 0, stream>>>(codes, scales, A2, B2, Wq, x, xb);
  k_gemm8<<<512, 512, 0, stream>>>(xb, Wq, bias, out);
}

// Round 15
// 296.297 us; speedup vs baseline: 1.2883x; 1.0009x over previous
//
#include <hip/hip_runtime.h>
#include <cstdint>
#include <type_traits>
#include <utility>

// ---------------------------------------------------------------------------
// SOARALinearLayer: out = x @ (W_deq + B2@A2)^T + bias
//   A2 = lora_A @ R_v, B2 = R_u @ lora_B (butterflies folded into LoRA factors)
// => one bf16 MFMA GEMM (M=8192, N=4096, K=4096) + tiny prep.
// R15: retirement-ordered interleave in the GEMM — per-i fragment reloads
// placed immediately after the last MFMA consuming that fragment, so ds_reads
// drain UNDER the remaining MFMAs (LDS pipe || matrix pipe) instead of
// serializing post-barrier. VMC positions unchanged w.r.t. VMEM queue.
// Prep = R13/R14 (k_rot + k_fused). 
// ---------------------------------------------------------------------------

typedef unsigned short u16;
typedef unsigned int   u32;
typedef short  s16x8 __attribute__((ext_vector_type(8)));
typedef __bf16 b16x8 __attribute__((ext_vector_type(8)));
typedef float  f32x4 __attribute__((ext_vector_type(4)));
typedef int    i32x4 __attribute__((ext_vector_type(4)));

#define SCALING 1.0f   /* ALPHA/RANK = 32/32 */

__device__ __forceinline__ u16 f2bf(float f) {
  u32 u = __builtin_bit_cast(u32, f);
  u += 0x7FFFu + ((u >> 16) & 1u);
  return (u16)(u >> 16);
}

template <typename T, typename = void>
struct mfma_takes_i16 : std::false_type {};
template <typename T>
struct mfma_takes_i16<T, std::void_t<decltype(__builtin_amdgcn_mfma_f32_16x16x32_bf16(
    std::declval<T>(), std::declval<T>(), std::declval<f32x4>(), 0, 0, 0))>>
    : std::true_type {};

template <typename T>
__device__ __forceinline__ f32x4 mfma_bf16(T a, T b, f32x4 c) {
  if constexpr (mfma_takes_i16<T>::value) {
    return __builtin_amdgcn_mfma_f32_16x16x32_bf16(a, b, c, 0, 0, 0);
  } else {
    return __builtin_amdgcn_mfma_f32_16x16x32_bf16(
        __builtin_bit_cast(b16x8, a), __builtin_bit_cast(b16x8, b), c, 0, 0, 0);
  }
}

__device__ __forceinline__ void gload_lds16(const void* g, void* l) {
  __builtin_amdgcn_global_load_lds((const __attribute__((address_space(1))) u32*)g,
                                   (__attribute__((address_space(3))) u32*)l,
                                   16, 0, 0);
}

// ===========================================================================
// Kernel 1: rotations. blocks 0-31: A2 = lora_A @ R_v; 32-63: B2 = R_u @ B.
// __sincosf: thetas ~N(0,0.02); error << bf16 quantization downstream.
// ===========================================================================
__global__ __launch_bounds__(256) void k_rot(const float* __restrict__ A,
                                             const float* __restrict__ thA,
                                             const float* __restrict__ B,
                                             const float* __restrict__ thB,
                                             float* __restrict__ A2,
                                             float* __restrict__ B2) {
  __shared__ float buf[4096];
  const int t = threadIdx.x;
  if (blockIdx.x < 32) {
    const int row = blockIdx.x;
    const float* src = A + (size_t)row * 4096;
    for (int p = 0; p < 16; ++p) buf[p * 256 + t] = src[p * 256 + t];
    __syncthreads();
    for (int j = 0; j < 12; ++j) {
      const int k = 4096 >> j;
      const int half = k >> 1;
      const int lh = 11 - j;
      for (int p = 0; p < 8; ++p) {
        int tp = p * 256 + t;
        int b = tp >> lh;
        int i = tp & (half - 1);
        int pi = b * k + i;
        int qi = pi + half;
        float s, c;
        __sincosf(thA[j * 2048 + tp], &s, &c);
        float xp = buf[pi], xq = buf[qi];
        buf[pi] = c * xp + s * xq;
        buf[qi] = -s * xp + c * xq;
      }
      __syncthreads();
    }
    for (int p = 0; p < 16; ++p) A2[(size_t)row * 4096 + p * 256 + t] = buf[p * 256 + t];
  } else {
    const int col = blockIdx.x - 32;
    for (int p = 0; p < 16; ++p) buf[p * 256 + t] = B[(size_t)(p * 256 + t) * 32 + col];
    __syncthreads();
    for (int j = 11; j >= 0; --j) {
      const int k = 4096 >> j;
      const int half = k >> 1;
      const int lh = 11 - j;
      for (int p = 0; p < 8; ++p) {
        int tp = p * 256 + t;
        int b = tp >> lh;
        int i = tp & (half - 1);
        int pi = b * k + i;
        int qi = pi + half;
        float s, c;
        __sincosf(thB[j * 2048 + tp], &s, &c);
        float xp = buf[pi], xq = buf[qi];
        buf[pi] = c * xp - s * xq;
        buf[qi] = s * xp + c * xq;
      }
      __syncthreads();
    }
    for (int p = 0; p < 16; ++p)
      B2[(size_t)(p * 256 + t) * 32 + col] = SCALING * buf[p * 256 + t];
  }
}

// ===========================================================================
// Kernel 2 (fused): blocks 0-1023: W' build; blocks 1024-3071: x -> bf16.
// Disjoint outputs, race-free.
// ===========================================================================
__global__ __launch_bounds__(256) void k_fused(const int* __restrict__ codes,
                                               const float* __restrict__ scales,
                                               const float* __restrict__ A2,
                                               const float* __restrict__ B2,
                                               u16* __restrict__ Wq,
                                               const float* __restrict__ x,
                                               u16* __restrict__ xb) {
  const int t = threadIdx.x;
  if (blockIdx.x >= 1024) {
    const size_t stride = (size_t)2048 * 256 * 8;
    size_t i = ((size_t)(blockIdx.x - 1024) * 256 + t) * 8;
#pragma unroll
    for (int it = 0; it < 8; ++it, i += stride) {
      f32x4 a = *(const f32x4*)(x + i);
      f32x4 b = *(const f32x4*)(x + i + 4);
      s16x8 o;
      o[0] = (short)f2bf(a[0]); o[1] = (short)f2bf(a[1]);
      o[2] = (short)f2bf(a[2]); o[3] = (short)f2bf(a[3]);
      o[4] = (short)f2bf(b[0]); o[5] = (short)f2bf(b[1]);
      o[6] = (short)f2bf(b[2]); o[7] = (short)f2bf(b[3]);
      *(s16x8*)(xb + i) = o;
    }
    return;
  }
  __shared__ float A2s[32][128];
  __shared__ float B2t[32][128];
  const int n0 = (blockIdx.x >> 5) << 7;
  const int k0 = (blockIdx.x & 31) << 7;

#pragma unroll
  for (int q = 0; q < 4; ++q) {
    int f = (q * 256 + t) * 4;
    int r = f >> 7, c = f & 127;
    *(f32x4*)&A2s[r][c] = *(const f32x4*)(A2 + (size_t)r * 4096 + k0 + c);
  }
#pragma unroll
  for (int q = 0; q < 4; ++q) {
    int f = (q * 256 + t) * 4;
    int i = f >> 5, r = f & 31;
    f32x4 v = *(const f32x4*)(B2 + (size_t)(n0 + i) * 32 + r);
    B2t[r][i] = v[0]; B2t[r + 1][i] = v[1]; B2t[r + 2][i] = v[2]; B2t[r + 3][i] = v[3];
  }
  __syncthreads();

  const int tr = t >> 4, tc = t & 15;
  const int kg = k0 + tc * 8;
  float acc[8][8];
#pragma unroll
  for (int i = 0; i < 8; ++i) {
    const int n = n0 + tr * 8 + i;
    const float sc = scales[((size_t)n << 6) + (kg >> 6)];
    const i32x4 c0 = *(const i32x4*)(codes + (size_t)n * 4096 + kg);
    const i32x4 c1 = *(const i32x4*)(codes + (size_t)n * 4096 + kg + 4);
#pragma unroll
    for (int e = 0; e < 4; ++e) {
      acc[i][e]     = (float)(c0[e] - 8) * sc;
      acc[i][4 + e] = (float)(c1[e] - 8) * sc;
    }
  }
#pragma unroll
  for (int r = 0; r < 32; ++r) {
    const f32x4 a0 = *(const f32x4*)&A2s[r][tc * 8];
    const f32x4 a1 = *(const f32x4*)&A2s[r][tc * 8 + 4];
    const f32x4 b0 = *(const f32x4*)&B2t[r][tr * 8];
    const f32x4 b1 = *(const f32x4*)&B2t[r][tr * 8 + 4];
#pragma unroll
    for (int i = 0; i < 4; ++i) {
#pragma unroll
      for (int e = 0; e < 4; ++e) {
        acc[i][e]         += b0[i] * a0[e];
        acc[i][4 + e]     += b0[i] * a1[e];
        acc[4 + i][e]     += b1[i] * a0[e];
        acc[4 + i][4 + e] += b1[i] * a1[e];
      }
    }
  }
#pragma unroll
  for (int i = 0; i < 8; ++i) {
    const int n = n0 + tr * 8 + i;
    s16x8 o;
#pragma unroll
    for (int e = 0; e < 8; ++e) o[e] = (short)f2bf(acc[i][e]);
    *(s16x8*)(Wq + (size_t)n * 4096 + kg) = o;
  }
}

// ===========================================================================
// Main GEMM, 256x256 tile, BK=64, 4 segments, retirement-ordered interleave.
// VMEM order + VMC queue positions identical to the R12 champion; ds_reads
// now sit in the MFMA stream right after their register's last use.
// ===========================================================================
#define BAR()    __builtin_amdgcn_s_barrier()
#define VMC(n)   do { asm volatile("s_waitcnt vmcnt(" #n ")" ::: "memory"); \
                      __builtin_amdgcn_sched_barrier(0); } while (0)

template <int QM>
__device__ __forceinline__ void load_a(s16x8 a[4][2], const u16* as, int wm, int lane) {
  const int rl = lane & 15, sl = lane >> 4;
#pragma unroll
  for (int i = 0; i < 4; ++i) {
    const int row = QM * 128 + wm + i * 16 + rl;
#pragma unroll
    for (int kk = 0; kk < 2; ++kk) {
      const int slot = kk * 4 + sl;
      a[i][kk] = *(const s16x8*)(as + row * 64 + ((slot ^ (row & 7)) << 3));
    }
  }
}

template <int QM, int I>
__device__ __forceinline__ void load_a_one(s16x8 a[4][2], const u16* as, int wm, int lane) {
  const int rl = lane & 15, sl = lane >> 4;
  const int row = QM * 128 + wm + I * 16 + rl;
#pragma unroll
  for (int kk = 0; kk < 2; ++kk) {
    const int slot = kk * 4 + sl;
    a[I][kk] = *(const s16x8*)(as + row * 64 + ((slot ^ (row & 7)) << 3));
  }
}

template <int QN>
__device__ __forceinline__ void load_b(s16x8 b[2][2], const u16* bs, int wn, int lane) {
  const int rl = lane & 15, sl = lane >> 4;
#pragma unroll
  for (int j = 0; j < 2; ++j) {
    const int row = QN * 128 + wn + j * 16 + rl;
#pragma unroll
    for (int kk = 0; kk < 2; ++kk) {
      const int slot = kk * 4 + sl;
      b[j][kk] = *(const s16x8*)(bs + row * 64 + ((slot ^ (row & 7)) << 3));
    }
  }
}

template <int QM, int QN>
__device__ __forceinline__ void mma16(f32x4 acc[8][4], s16x8 a[4][2], s16x8 b[2][2]) {
#pragma unroll
  for (int kk = 0; kk < 2; ++kk)
#pragma unroll
    for (int i = 0; i < 4; ++i)
#pragma unroll
      for (int j = 0; j < 2; ++j)
        acc[QM * 4 + i][QN * 2 + j] = mfma_bf16(a[i][kk], b[j][kk], acc[QM * 4 + i][QN * 2 + j]);
}

// 4 MFMAs consuming only a[I] (both kk, both j) — after this a[I] is dead.
template <int QM, int QN, int I>
__device__ __forceinline__ void mma_one(f32x4 acc[8][4], s16x8 a[4][2], s16x8 b[2][2]) {
#pragma unroll
  for (int kk = 0; kk < 2; ++kk)
#pragma unroll
    for (int j = 0; j < 2; ++j)
      acc[QM * 4 + I][QN * 2 + j] = mfma_bf16(a[I][kk], b[j][kk], acc[QM * 4 + I][QN * 2 + j]);
}

__global__ __launch_bounds__(512, 2) void k_gemm8(const u16* __restrict__ Abf,
                                                  const u16* __restrict__ Bbf,
                                                  const float* __restrict__ bias,
                                                  float* __restrict__ out) {
  __shared__ __align__(16) u16 As[2][256 * 64];
  __shared__ __align__(16) u16 Bs[2][256 * 64];

  const int bid = blockIdx.x;
  const int wg = (bid & 7) * 64 + (bid >> 3);   // 512 % 8 == 0: bijective XCD swizzle
  const int mt = wg >> 4, nt = wg & 15;
  const int m0 = mt << 8, n0 = nt << 8;
  const int tid = threadIdx.x;
  const int lane = tid & 63;
  const int wid = tid >> 6;
  const int wm = (wid >> 2) * 64;   // row sub-offset within each 128-row half
  const int wn = (wid & 3) * 32;    // col sub-offset within each 128-col half

  int rowc[2], swzc[2];
#pragma unroll
  for (int c = 0; c < 2; ++c) {
    const int flat = (c * 512 + tid) * 8;
    rowc[c] = flat >> 6;
    const int slot = (flat >> 3) & 7;
    swzc[c] = (slot ^ (rowc[c] & 7)) << 3;   // inverse-swizzled global source
  }
  const u16* Ap0 = Abf + ((size_t)m0) * 4096;
  const u16* Ap1 = Abf + ((size_t)(m0 + 128)) * 4096;
  const u16* Bp0 = Bbf + ((size_t)n0) * 4096;
  const u16* Bp1 = Bbf + ((size_t)(n0 + 128)) * 4096;

#define STAGE(gpan, kt, ldsbase)                                              \
  do {                                                                        \
    _Pragma("unroll")                                                         \
    for (int c = 0; c < 2; ++c)                                               \
      gload_lds16((gpan) + (size_t)rowc[c] * 4096 + (kt) * 64 + swzc[c],      \
                  (ldsbase) + (c * 512 + tid) * 8);                           \
  } while (0)

  f32x4 acc[8][4] = {};
  s16x8 a[4][2], b0[2][2], b1[2][2];

  // ---- prologue: K0 full -> buf0; K1.A0 -> buf1.A0; K1.B1 -> buf1.B1 ----
  STAGE(Ap0, 0, As[0]);
  STAGE(Ap1, 0, As[0] + 8192);
  STAGE(Bp0, 0, Bs[0]);
  STAGE(Bp1, 0, Bs[0] + 8192);
  STAGE(Ap0, 1, As[1]);
  STAGE(Bp1, 1, Bs[1] + 8192);
  VMC(4);          // buf0 (8 ops) landed; buf1.A0/B1 may remain in flight
  BAR();
  // pre-load seg1 fragments (buf0, valid after VMC(4))
  load_a<0>(a, As[0], wm, lane);
  load_b<0>(b0, Bs[0], wn, lane);
  load_b<1>(b1, Bs[0], wn, lane);

#pragma unroll 1
  for (int it = 0; it < 32; ++it) {
    const int kn1 = 2 * it + 1;
    const int ktA = (2 * it + 2 < 64) ? 2 * it + 2 : 63;  // clamped tail (dead stages)
    const int ktB = (2 * it + 3 < 64) ? 2 * it + 3 : 63;

    // ---- seg1: S1 buf1.B0; S2 buf1.A1; mma(0,0); VMC(8); mma(0,1)||read a1(buf0) ----
    STAGE(Bp0, kn1, Bs[1]);
    STAGE(Ap1, kn1, As[1] + 8192);
    __builtin_amdgcn_s_setprio(1);
    mma16<0, 0>(acc, a, b0);
    VMC(8);                                  // prev S6 (buf0.A1) drained
    mma_one<0, 1, 0>(acc, a, b1); load_a_one<1, 0>(a, As[0], wm, lane);
    mma_one<0, 1, 1>(acc, a, b1); load_a_one<1, 1>(a, As[0], wm, lane);
    mma_one<0, 1, 2>(acc, a, b1); load_a_one<1, 2>(a, As[0], wm, lane);
    mma_one<0, 1, 3>(acc, a, b1); load_a_one<1, 3>(a, As[0], wm, lane);
    __builtin_amdgcn_s_setprio(0);
    BAR();
    // ---- seg2: S3 buf0.A0; S4 buf0.B1; mma(1,1); VMC(6); mma(1,0)||read buf1 ----
    STAGE(Ap0, ktA, As[0]);
    STAGE(Bp1, ktA, Bs[0] + 8192);
    __builtin_amdgcn_s_setprio(1);
    mma16<1, 1>(acc, a, b1);
    VMC(6);                                  // buf1 (K 2it+1) fully landed
    load_b<1>(b1, Bs[1], wn, lane);          // b1 dead after mma16<1,1>
    mma_one<1, 0, 0>(acc, a, b0); load_a_one<0, 0>(a, As[1], wm, lane);
    mma_one<1, 0, 1>(acc, a, b0); load_a_one<0, 1>(a, As[1], wm, lane);
    mma_one<1, 0, 2>(acc, a, b0); load_a_one<0, 2>(a, As[1], wm, lane);
    mma_one<1, 0, 3>(acc, a, b0); load_a_one<0, 3>(a, As[1], wm, lane);
    load_b<0>(b0, Bs[1], wn, lane);          // b0 dead after mma(1,0)
    __builtin_amdgcn_s_setprio(0);
    BAR();
    // ---- seg3: S5 buf0.B0; S6 buf0.A1; mma(0,0); VMC(8); mma(0,1)||read a1(buf1) ----
    STAGE(Bp0, ktA, Bs[0]);
    STAGE(Ap1, ktA, As[0] + 8192);
    __builtin_amdgcn_s_setprio(1);
    mma16<0, 0>(acc, a, b0);
    VMC(8);                                  // S2 (buf1.A1) drained
    mma_one<0, 1, 0>(acc, a, b1); load_a_one<1, 0>(a, As[1], wm, lane);
    mma_one<0, 1, 1>(acc, a, b1); load_a_one<1, 1>(a, As[1], wm, lane);
    mma_one<0, 1, 2>(acc, a, b1); load_a_one<1, 2>(a, As[1], wm, lane);
    mma_one<0, 1, 3>(acc, a, b1); load_a_one<1, 3>(a, As[1], wm, lane);
    __builtin_amdgcn_s_setprio(0);
    BAR();
    // ---- seg4: S7 buf1.A0; S8 buf1.B1; mma(1,1); VMC(6); mma(1,0)||read buf0 ----
    STAGE(Ap0, ktB, As[1]);
    STAGE(Bp1, ktB, Bs[1] + 8192);
    __builtin_amdgcn_s_setprio(1);
    mma16<1, 1>(acc, a, b1);
    VMC(6);                                  // buf0 (K 2it+2) fully landed
    load_b<1>(b1, Bs[0], wn, lane);
    mma_one<1, 0, 0>(acc, a, b0); load_a_one<0, 0>(a, As[0], wm, lane);
    mma_one<1, 0, 1>(acc, a, b0); load_a_one<0, 1>(a, As[0], wm, lane);
    mma_one<1, 0, 2>(acc, a, b0); load_a_one<0, 2>(a, As[0], wm, lane);
    mma_one<1, 0, 3>(acc, a, b0); load_a_one<0, 3>(a, As[0], wm, lane);
    load_b<0>(b0, Bs[0], wn, lane);
    __builtin_amdgcn_s_setprio(0);
    BAR();
  }

  // ---- epilogue: C/D layout col = lane&15, row = (lane>>4)*4 + v ----
  const int rl = lane & 15, rg = lane >> 4;
  float bv[4];
#pragma unroll
  for (int j = 0; j < 4; ++j)
    bv[j] = bias[n0 + (j >> 1) * 128 + wn + (j & 1) * 16 + rl];
#pragma unroll
  for (int i = 0; i < 8; ++i) {
    const int row0 = m0 + (i >> 2) * 128 + wm + (i & 3) * 16 + rg * 4;
#pragma unroll
    for (int j = 0; j < 4; ++j) {
      const int col = n0 + (j >> 1) * 128 + wn + (j & 1) * 16 + rl;
#pragma unroll
      for (int v = 0; v < 4; ++v)
        out[(size_t)(row0 + v) * 4096 + col] = acc[i][j][v] + bv[j];
    }
  }
#undef STAGE
}

// ===========================================================================
extern "C" void kernel_launch(void* const* d_in, const int* in_sizes, int n_in,
                              void* d_out, int out_size, void* d_ws, size_t ws_size,
                              hipStream_t stream) {
  const float* x      = (const float*)d_in[0];
  const int*   codes  = (const int*)d_in[1];
  const float* scales = (const float*)d_in[2];
  const float* th_v   = (const float*)d_in[3];
  const float* th_u   = (const float*)d_in[4];
  const float* lA     = (const float*)d_in[5];
  const float* lB     = (const float*)d_in[6];
  const float* bias   = (const float*)d_in[7];
  float* out = (float*)d_out;

  char* ws = (char*)d_ws;
  float* A2 = (float*)ws;                              // 512 KB
  float* B2 = (float*)(ws + (512u << 10));             // 512 KB
  u16*   Wq = (u16*)(ws + (1u << 20));                 // 32 MB
  u16*   xb = (u16*)(ws + (1u << 20) + (32u << 20));   // 64 MB

  k_rot<<<64, 256, 0, stream>>>(lA, th_v, lB, th_u, A2, B2);
  k_fused<<<3072, 256, 0, stream>>>(codes, scales, A2, B2, Wq, x, xb);
  k_gemm8<<<512, 512, 0, stream>>>(xb, Wq, bias, out);
}